// Round 7
// baseline (947.271 us; speedup 1.0000x reference)
//
#include <hip/hip_runtime.h>
#include <math.h>
#include <stdint.h>

#define B_ 4
#define C_ 256
#define H_ 128
#define W_ 128
#define NPIX (H_*W_)

typedef short bf16x8 __attribute__((ext_vector_type(8)));
typedef int   i32x4  __attribute__((ext_vector_type(4)));
typedef float f32x4  __attribute__((ext_vector_type(4)));
typedef float f32x16 __attribute__((ext_vector_type(16)));
typedef unsigned short u16x4 __attribute__((ext_vector_type(4)));

// ---- LDS map: x double buffer only; epilogue reuses [0, 64K) ----
#define XSZ   41984              // 328 slots * 128 B (one 64-c quarter of 18x18 halo)
#define SCR   (2*XSZ)            // 83968: 1 KB scratch for dummy stage ops
#define LDS_TOTAL (SCR + 1024)   // 84992

__device__ __forceinline__ unsigned short f2bf_rne(float v) {
    uint32_t b = __float_as_uint(v);
    return (unsigned short)((b + 0x7fff + ((b >> 16) & 1)) >> 16);
}
__device__ __forceinline__ float bf2f(unsigned short h) {
    return __uint_as_float(((uint32_t)h) << 16);
}

// ---- prep: W -> wb2[sl][oq][mo][ks][kh][o32][e8], sl = qt*9 + k (1.125 MB)
// Per-lane A-load becomes one fully-coalesced dwordx4: addr = base + l*16.
__global__ __launch_bounds__(256)
void prep_w2(const float* __restrict__ wg, unsigned short* __restrict__ wb2,
             unsigned short* __restrict__ zb) {
    if (blockIdx.x == 2304) { if (threadIdx.x < 128) zb[threadIdx.x] = 0; return; }
    int f = blockIdx.x * 256 + threadIdx.x;          // < 589824
    int sl = f >> 14;
    int r = f & 16383;
    int oq = r >> 12;  r &= 4095;
    int mo = r >> 11;  r &= 2047;
    int ks = r >> 9;   r &= 511;
    int kh = r >> 8;
    int o5 = (r >> 3) & 31;
    int e  = r & 7;
    int o = oq * 64 + mo * 32 + o5;
    int u = ks * 2 + kh;
    int qt = sl / 9, k = sl - qt * 9;
    int c = qt * 64 + u * 8 + e;
    wb2[f] = f2bf_rne(wg[(o * C_ + c) * 9 + k]);
}

// ---- prep: retina fp32 (B,C,H,W) -> channel-last hi/lo bf16 shadows (B,H,W,C)
__global__ __launch_bounds__(256)
void prep_split(const float* __restrict__ retina, unsigned short* __restrict__ hi,
                unsigned short* __restrict__ lo) {
    __shared__ unsigned int t[64][65];
    int bid = blockIdx.x;
    const int wt = bid & 1;        bid >>= 1;
    const int h  = bid & 127;      bid >>= 7;
    const int ct = bid & 3;        const int b = bid >> 2;
    const int tid = threadIdx.x;
    const int ci4 = tid >> 6, wi = tid & 63;
    #pragma unroll
    for (int cc = 0; cc < 16; ++cc) {
        int c_loc = cc * 4 + ci4;
        float v = retina[((size_t)(b * C_ + ct * 64 + c_loc) * H_ + h) * W_ + wt * 64 + wi];
        unsigned short hv = f2bf_rne(v);
        unsigned short lv = f2bf_rne(v - bf2f(hv));
        t[c_loc][wi] = (unsigned)hv | ((unsigned)lv << 16);
    }
    __syncthreads();
    const int p = tid >> 2, j = tid & 3;
    size_t base = (((size_t)(b * H_ + h) * W_ + wt * 64 + p) << 8) + ct * 64 + j * 16;
    u16x4 hv4[4], lv4[4];
    #pragma unroll
    for (int e = 0; e < 16; ++e) {
        unsigned u = t[j * 16 + e][p];
        hv4[e >> 2][e & 3] = (unsigned short)(u & 0xffffu);
        lv4[e >> 2][e & 3] = (unsigned short)(u >> 16);
    }
    #pragma unroll
    for (int q2 = 0; q2 < 4; ++q2) {
        *(u16x4*)(hi + base + q2 * 4) = hv4[q2];
        *(u16x4*)(lo + base + q2 * 4) = lv4[q2];
    }
}

// ---- x staging: 6 global_load_lds ops/wave, wave-uniform; swizzle folded into src
__device__ __forceinline__ void stage_x(const unsigned short* __restrict__ hi_in,
                                        const unsigned short* __restrict__ zb,
                                        char* smem, int xoff, int b, int tr, int tc,
                                        int qt, int wid, int l) {
    const int slot_r = l >> 3, sub = l & 7;
    #pragma unroll
    for (int op = 0; op < 6; ++op) {
        const int sbase = (op << 6) + (wid << 3);    // 0..383, wave-uniform
        const int s = sbase + slot_r;
        const int rr = (s * 3641) >> 16;             // s/18 for s<=383
        const int hc = s - rr * 18;
        const int h = tr * 16 + rr - 1;
        const int w = tc * 16 + hc - 1;
        const unsigned short* src;
        int dst;
        if (sbase < 328) {
            dst = xoff + (sbase << 7);
            if ((unsigned)h < 128u && (unsigned)w < 128u)
                src = hi_in + ((((size_t)(b * 128 + h) << 7) + w) << 8) + (qt << 6)
                            + ((sub ^ (s & 7)) << 3);
            else
                src = zb + (sub << 3);
        } else {
            dst = SCR;
            src = zb + (sub << 3);
        }
        __builtin_amdgcn_global_load_lds(
            (const __attribute__((address_space(1))) uint32_t*)src,
            (__attribute__((address_space(3))) uint32_t*)(smem + dst), 16, 0, 0);
    }
    __builtin_amdgcn_sched_barrier(0);
}

struct Aset { bf16x8 f[2][4]; };   // [mo][ks] : 32 VGPR

// ---- main step: 8 waves (4 o-quarters x 2 px-halves), A in registers from L2,
//      B from LDS, barriers only at qt boundaries, LDS-transpose epilogue
__global__ __launch_bounds__(512, 2)
void nca_v8(const unsigned short* __restrict__ hi_in,
            const unsigned short* __restrict__ lo_in,
            const unsigned short* __restrict__ wb2,
            const unsigned short* __restrict__ zb,
            const float* __restrict__ mask,
            unsigned short* __restrict__ hi_out,
            unsigned short* __restrict__ lo_out)
{
    extern __shared__ char smem[];
    const int tid = threadIdx.x;
    const int l = tid & 63, wid = tid >> 6;          // 8 waves
    const int oq = wid & 3, ph2 = wid >> 2;          // o-quarter, pixel-half
    const int khalf = l >> 5;
    const int col = l & 15, rowin = (l >> 4) & 1;

    int bid = blockIdx.x;
    const int tc = bid & 7; bid >>= 3;
    const int tr = bid & 7; const int b = bid >> 3;

    // mask bits (9 taps x 4 row-pairs), pinned before staging
    unsigned long long mbits = 0ull;
    #pragma unroll
    for (int k = 0; k < 9; ++k) {
        #pragma unroll
        for (int n = 0; n < 4; ++n) {
            const int h = tr * 16 + ph2 * 8 + n * 2 + rowin;
            const int w = tc * 16 + col;
            unsigned long long bit = (mask[k * NPIX + h * W_ + w] != 0.f) ? 1ull : 0ull;
            mbits |= bit << (k * 4 + n);
        }
    }
    __builtin_amdgcn_sched_barrier(0);

    // prologue: stage x q0,q1; load A slices 0,1 into regs
    stage_x(hi_in, zb, smem, 0,   b, tr, tc, 0, wid, l);
    stage_x(hi_in, zb, smem, XSZ, b, tr, tc, 1, wid, l);

    const char* abase = (const char*)wb2 + (oq << 13) + (l << 4);
    Aset a0, a1;
    #pragma unroll
    for (int mo = 0; mo < 2; ++mo)
        #pragma unroll
        for (int ks = 0; ks < 4; ++ks) {
            a0.f[mo][ks] = *(const bf16x8*)(abase +     0 + mo * 4096 + ks * 1024);
            a1.f[mo][ks] = *(const bf16x8*)(abase + 32768 + mo * 4096 + ks * 1024);
        }
    asm volatile("s_waitcnt vmcnt(16)" ::: "memory");   // stages done; A0/A1 in flight
    __builtin_amdgcn_sched_barrier(0);
    __builtin_amdgcn_s_barrier();

    int sB[4];
    #pragma unroll
    for (int n = 0; n < 4; ++n) sB[n] = (ph2 * 8 + n * 2 + rowin) * 18 + col;

    f32x16 zv;
    #pragma unroll
    for (int r = 0; r < 16; ++r) zv[r] = 0.f;
    f32x16 acc[2][4];
    #pragma unroll
    for (int mo = 0; mo < 2; ++mo)
        #pragma unroll
        for (int n = 0; n < 4; ++n) acc[mo][n] = zv;

    #pragma unroll
    for (int sl = 0; sl < 36; ++sl) {
        const int qt = sl / 9, k = sl - qt * 9;
        const int dy = k / 3, dx = k - dy * 3;
        const int doff = dy * 18 + dx;
        const char* xbuf = smem + ((qt & 1) ? XSZ : 0);
        const unsigned mk = (unsigned)(mbits >> (k * 4));
        Aset& cur = (sl & 1) ? a1 : a0;

        __builtin_amdgcn_s_setprio(1);
        #pragma unroll
        for (int ks = 0; ks < 4; ++ks) {
            const int u = ks * 2 + khalf;
            bf16x8 bv[4];
            #pragma unroll
            for (int n = 0; n < 4; ++n) {
                const int spx = sB[n] + doff;
                i32x4 braw = *(const i32x4*)(xbuf + spx * 128 + ((u ^ (spx & 7)) << 4));
                const int mm = -(int)((mk >> n) & 1u);
                #pragma unroll
                for (int w4 = 0; w4 < 4; ++w4) braw[w4] &= mm;   // binary mask, exact
                bv[n] = __builtin_bit_cast(bf16x8, braw);
            }
            #pragma unroll
            for (int mo = 0; mo < 2; ++mo)
                #pragma unroll
                for (int n = 0; n < 4; ++n)
                    acc[mo][n] = __builtin_amdgcn_mfma_f32_32x32x16_bf16(cur.f[mo][ks], bv[n], acc[mo][n], 0, 0, 0);
        }
        __builtin_amdgcn_s_setprio(0);

        // prefetch A slice sl+2 into the just-consumed set (compiler tracks deps)
        if (sl + 2 < 36) {
            const char* base2 = abase + (size_t)(sl + 2) * 32768;
            #pragma unroll
            for (int mo = 0; mo < 2; ++mo)
                #pragma unroll
                for (int ks = 0; ks < 4; ++ks)
                    cur.f[mo][ks] = *(const bf16x8*)(base2 + mo * 4096 + ks * 1024);
        }
        // stage x for qt+1 mid-quarter (its buffer became free at previous barrier)
        if (k == 4 && (qt == 1 || qt == 2))
            stage_x(hi_in, zb, smem, ((qt + 1) & 1) ? XSZ : 0, b, tr, tc, qt + 1, wid, l);
        // quarter boundary: ensure stage retired (32 newer A-ops exist), then barrier
        if (k == 8 && qt < 3) {
            __builtin_amdgcn_sched_barrier(0);
            if (qt >= 1) { asm volatile("s_waitcnt vmcnt(24)" ::: "memory"); }
            __builtin_amdgcn_sched_barrier(0);
            __builtin_amdgcn_s_barrier();
        }
    }

    // ---- epilogue: 4 phases of 64 px; LDS transpose -> coalesced hi/lo RMW
    __syncthreads();
    #pragma unroll 1
    for (int f = 0; f < 4; ++f) {
        if (ph2 == (f >> 1)) {
            #pragma unroll
            for (int nn = 0; nn < 2; ++nn) {
                const int n = (f & 1) * 2 + nn;
                const int px = (nn * 2 + rowin) * 16 + col;   // 0..63
                #pragma unroll
                for (int mo = 0; mo < 2; ++mo)
                    #pragma unroll
                    for (int rq = 0; rq < 4; ++rq) {
                        const int u = oq * 16 + mo * 8 + rq * 2 + khalf;
                        f32x4 v;
                        v[0] = acc[mo][n][rq * 4 + 0];
                        v[1] = acc[mo][n][rq * 4 + 1];
                        v[2] = acc[mo][n][rq * 4 + 2];
                        v[3] = acc[mo][n][rq * 4 + 3];
                        *(f32x4*)(smem + px * 1024 + ((u ^ (px & 7)) << 4)) = v;
                    }
            }
        }
        __syncthreads();
        {
            const int px = tid >> 3, q = tid & 7;
            const int h = tr * 16 + f * 4 + (px >> 4);
            const int w = tc * 16 + (px & 15);
            const size_t pixbase = ((size_t)((b * 128 + h) * 128 + w)) << 8;
            #pragma unroll
            for (int j = 0; j < 8; ++j) {
                const int u = q + 8 * j;
                const f32x4 d4 = *(const f32x4*)(smem + px * 1024 + ((u ^ (px & 7)) << 4));
                const size_t a2 = pixbase + 4 * (size_t)u;
                const u16x4 h4 = *(const u16x4*)(hi_in + a2);
                const u16x4 l4 = *(const u16x4*)(lo_in + a2);
                u16x4 ho, lo2;
                #pragma unroll
                for (int r = 0; r < 4; ++r) {
                    const float xv = bf2f(h4[r]) + bf2f(l4[r]);
                    const float d = d4[r];
                    const float xn = xv + d / (1.f + fabsf(d));
                    ho[r] = f2bf_rne(xn);
                    lo2[r] = f2bf_rne(xn - bf2f(ho[r]));
                }
                *(u16x4*)(hi_out + a2) = ho;
                *(u16x4*)(lo_out + a2) = lo2;
            }
        }
        if (f < 3) __syncthreads();
    }
}

// ---- final: channel-last hi/lo shadows -> fp32 (B,C,H,W) via LDS transpose
__global__ __launch_bounds__(256)
void shadows_to_f32(const unsigned short* __restrict__ hi,
                    const unsigned short* __restrict__ lo,
                    float* __restrict__ out)
{
    __shared__ float t[64][132];
    int bid = blockIdx.x;
    const int ct = bid & 3;  bid >>= 2;
    const int h  = bid & 127; const int b = bid >> 7;
    const int tid = threadIdx.x;
    #pragma unroll
    for (int pass = 0; pass < 8; ++pass) {
        const int w = pass * 16 + (tid >> 4);
        const int c0 = (tid & 15) * 4;
        const size_t base = (((size_t)((b * 128 + h) * 128 + w)) << 8) + ct * 64 + c0;
        const u16x4 hv = *(const u16x4*)(hi + base);
        const u16x4 lv = *(const u16x4*)(lo + base);
        #pragma unroll
        for (int e = 0; e < 4; ++e) t[c0 + e][w] = bf2f(hv[e]) + bf2f(lv[e]);
    }
    __syncthreads();
    #pragma unroll
    for (int pass = 0; pass < 8; ++pass) {
        const int c = pass * 8 + (tid >> 5);
        const int w = (tid & 31) * 4;
        float4 v = make_float4(t[c][w], t[c][w + 1], t[c][w + 2], t[c][w + 3]);
        *(float4*)(out + ((size_t)(b * C_ + ct * 64 + c) * H_ + h) * W_ + w) = v;
    }
}

// ================= fp32 fallback (only if ws too small) =================
#define OT 64
#define TR 4
#define TC 16
#define CKC 16
__global__ __launch_bounds__(256)
void nca_step_f32(const float* __restrict__ xin, const float* __restrict__ wg,
                  const float* __restrict__ mask, float* __restrict__ xout)
{
    __shared__ __align__(16) float w_s[CKC][9][OT];
    __shared__ __align__(16) float x_s[CKC][TR + 2][20];
    const int tid = threadIdx.x;
    int bt = blockIdx.x;
    const int col_tile = bt & 7;  bt >>= 3;
    const int row_tile = bt & 31; bt >>= 5;
    const int ot = bt & 3;        const int b = bt >> 2;
    const int gr0 = row_tile * TR, gc0 = col_tile * TC, o_base = ot * OT;
    const int og = tid >> 4, pg = tid & 15;
    const int prow = pg >> 2, pcol4 = (pg & 3) * 4;
    const int orow = gr0 + prow, ocol0 = gc0 + pcol4;
    float mask_r[9][4];
#pragma unroll
    for (int k = 0; k < 9; ++k)
#pragma unroll
        for (int j = 0; j < 4; ++j)
            mask_r[k][j] = mask[k * NPIX + orow * W_ + (ocol0 + j)];
    float acc[4][4];
#pragma unroll
    for (int a = 0; a < 4; ++a)
#pragma unroll
        for (int j = 0; j < 4; ++j) acc[a][j] = 0.f;
    for (int chunk = 0; chunk < C_ / CKC; ++chunk) {
        const int c0 = chunk * CKC;
#pragma unroll
        for (int i = 0; i < 36; ++i) {
            const int flat = i * 256 + tid;
            const int o_l = flat / 144;
            const int r = flat - o_l * 144;
            const int c_l = r / 9;
            const int kk = r - c_l * 9;
            w_s[c_l][kk][o_l] = wg[(o_base + o_l) * (C_ * 9) + (c0 + c_l) * 9 + kk];
        }
#pragma unroll
        for (int i = 0; i < 7; ++i) {
            const int flat = i * 256 + tid;
            if (flat < CKC * 108) {
                const int c_l = flat / 108;
                const int r = flat - c_l * 108;
                const int row = r / 18, colx = r - row * 18;
                const int grow = gr0 - 1 + row, gcol = gc0 - 1 + colx;
                float v = 0.f;
                if ((unsigned)grow < (unsigned)H_ && (unsigned)gcol < (unsigned)W_)
                    v = xin[((b * C_ + c0 + c_l) * H_ + grow) * W_ + gcol];
                x_s[c_l][row][colx] = v;
            }
        }
        __syncthreads();
#pragma unroll
        for (int dyy = 0; dyy < 3; ++dyy) {
            float acck[3][4][4];
#pragma unroll
            for (int dxx = 0; dxx < 3; ++dxx)
#pragma unroll
                for (int a = 0; a < 4; ++a)
#pragma unroll
                    for (int j = 0; j < 4; ++j) acck[dxx][a][j] = 0.f;
#pragma unroll 4
            for (int c = 0; c < CKC; ++c) {
                const float4 xv4 = *(const float4*)&x_s[c][prow + dyy][pcol4];
                const float2 xv2 = *(const float2*)&x_s[c][prow + dyy][pcol4 + 4];
                const float xv[6] = {xv4.x, xv4.y, xv4.z, xv4.w, xv2.x, xv2.y};
#pragma unroll
                for (int dxx = 0; dxx < 3; ++dxx) {
                    const float4 wv = *(const float4*)&w_s[c][dyy * 3 + dxx][og * 4];
                    const float wa[4] = {wv.x, wv.y, wv.z, wv.w};
#pragma unroll
                    for (int a = 0; a < 4; ++a)
#pragma unroll
                        for (int j = 0; j < 4; ++j)
                            acck[dxx][a][j] = fmaf(wa[a], xv[j + dxx], acck[dxx][a][j]);
                }
            }
#pragma unroll
            for (int dxx = 0; dxx < 3; ++dxx) {
                const int k = dyy * 3 + dxx;
#pragma unroll
                for (int a = 0; a < 4; ++a)
#pragma unroll
                    for (int j = 0; j < 4; ++j)
                        acc[a][j] = fmaf(mask_r[k][j], acck[dxx][a][j], acc[a][j]);
            }
        }
        __syncthreads();
    }
#pragma unroll
    for (int a = 0; a < 4; ++a) {
        const int o = o_base + og * 4 + a;
#pragma unroll
        for (int j = 0; j < 4; ++j) {
            const int idx = ((b * C_ + o) * H_ + orow) * W_ + (ocol0 + j);
            const float d = acc[a][j];
            xout[idx] = xin[idx] + d / (1.0f + fabsf(d));
        }
    }
}

extern "C" void kernel_launch(void* const* d_in, const int* in_sizes, int n_in,
                              void* d_out, int out_size, void* d_ws, size_t ws_size,
                              hipStream_t stream) {
    const float* retina = (const float*)d_in[0];
    const float* wg     = (const float*)d_in[1];
    const float* mask   = (const float*)d_in[2];
    float* out = (float*)d_out;

    const size_t need = 0x4200000;   // wb2+zb (2M) + hiA/loA (2x32M)

    if (ws_size >= need) {
        unsigned short* wb2 = (unsigned short*)d_ws;
        unsigned short* zb  = (unsigned short*)((char*)d_ws + 0x120000);
        unsigned short* hiA = (unsigned short*)((char*)d_ws + 0x200000);
        unsigned short* loA = (unsigned short*)((char*)d_ws + 0x2200000);
        unsigned short* hiB = (unsigned short*)d_out;              // first 32 MB of out
        unsigned short* loB = hiB + (size_t)B_ * NPIX * C_;        // second 32 MB

        hipFuncSetAttribute((const void*)nca_v8,
                            hipFuncAttributeMaxDynamicSharedMemorySize, LDS_TOTAL);

        prep_w2<<<2305, 256, 0, stream>>>(wg, wb2, zb);
        prep_split<<<4096, 256, 0, stream>>>(retina, hiB, loB);    // state starts in B (d_out)

        // B->A->B->A->B->A : final state lands in ws, then transpose into d_out
        nca_v8<<<256, 512, LDS_TOTAL, stream>>>(hiB, loB, wb2, zb, mask, hiA, loA);
        nca_v8<<<256, 512, LDS_TOTAL, stream>>>(hiA, loA, wb2, zb, mask, hiB, loB);
        nca_v8<<<256, 512, LDS_TOTAL, stream>>>(hiB, loB, wb2, zb, mask, hiA, loA);
        nca_v8<<<256, 512, LDS_TOTAL, stream>>>(hiA, loA, wb2, zb, mask, hiB, loB);
        nca_v8<<<256, 512, LDS_TOTAL, stream>>>(hiB, loB, wb2, zb, mask, hiA, loA);
        shadows_to_f32<<<2048, 256, 0, stream>>>(hiA, loA, out);
    } else {
        float* ws = (float*)d_ws;
        const int nblocks = B_ * (C_ / OT) * (H_ / TR) * (W_ / TC);
        const float* src = retina;
        float* dsts[5] = {out, ws, out, ws, out};
        for (int s = 0; s < 5; ++s) {
            nca_step_f32<<<dim3(nblocks), dim3(256), 0, stream>>>(src, wg, mask, dsts[s]);
            src = dsts[s];
        }
    }
}

// Round 8
// 645.940 us; speedup vs baseline: 1.4665x; 1.4665x over previous
//
#include <hip/hip_runtime.h>
#include <math.h>
#include <stdint.h>

#define B_ 4
#define C_ 256
#define H_ 128
#define W_ 128
#define NPIX (H_*W_)

typedef short bf16x8 __attribute__((ext_vector_type(8)));
typedef int   i32x4  __attribute__((ext_vector_type(4)));
typedef float f32x4  __attribute__((ext_vector_type(4)));
typedef float f32x16 __attribute__((ext_vector_type(16)));
typedef unsigned short u16x4 __attribute__((ext_vector_type(4)));
typedef unsigned short u16x8 __attribute__((ext_vector_type(8)));

// ---- LDS map (main kernel, 2 blocks/CU) ----
// x buffer: 192 slots (10x18 halo = 180 + 12 pad) * 64 B (32 c bf16), double-buffered
// W buffer: 16 KB slice (256 o * 32 c * 2 B), double-buffered
// epilogue reuses [0, 64 KB) as 64 px * 1 KB transpose buffer
#define XSL  192
#define XSZ2 (XSL*64)             // 12288
#define WOFF (2*XSZ2)             // 24576
#define WSL2 16384
#define LDS_TOTAL 66560           // >= 64K epilogue, >= 57344 main; 2 blocks/CU

__device__ __forceinline__ unsigned short f2bf_rne(float v) {
    uint32_t b = __float_as_uint(v);
    return (unsigned short)((b + 0x7fff + ((b >> 16) & 1)) >> 16);
}
__device__ __forceinline__ float bf2f(unsigned short h) {
    return __uint_as_float(((uint32_t)h) << 16);
}

// ---- prep: W -> wb3: 72 slices (sl = cq*9 + k, cq = 32-c chunk) of the exact
// 16 KB LDS image: [o][u'][e], u' = u ^ (o&3), c = cq*32 + u*8 + e.
__global__ __launch_bounds__(256)
void prep_w3(const float* __restrict__ wg, unsigned short* __restrict__ wb3,
             unsigned short* __restrict__ zb) {
    if (blockIdx.x == 2304) { if (threadIdx.x < 128) zb[threadIdx.x] = 0; return; }
    int f = blockIdx.x * 256 + threadIdx.x;          // < 589824
    int sl = f >> 13;
    int r = f & 8191;
    int o = r >> 5;
    int t = r & 31;
    int up = t >> 3, e = t & 7;
    int cq = sl / 9, k = sl - cq * 9;
    int u = up ^ (o & 3);
    int c = cq * 32 + u * 8 + e;
    wb3[f] = f2bf_rne(wg[(o * C_ + c) * 9 + k]);
}

// ---- prep: retina fp32 (B,C,H,W) -> channel-last hi/lo bf16 shadows (B,H,W,C)
__global__ __launch_bounds__(256)
void prep_split(const float* __restrict__ retina, unsigned short* __restrict__ hi,
                unsigned short* __restrict__ lo) {
    __shared__ unsigned int t[64][65];
    int bid = blockIdx.x;
    const int wt = bid & 1;        bid >>= 1;
    const int h  = bid & 127;      bid >>= 7;
    const int ct = bid & 3;        const int b = bid >> 2;
    const int tid = threadIdx.x;
    const int ci4 = tid >> 6, wi = tid & 63;
    #pragma unroll
    for (int cc = 0; cc < 16; ++cc) {
        int c_loc = cc * 4 + ci4;
        float v = retina[((size_t)(b * C_ + ct * 64 + c_loc) * H_ + h) * W_ + wt * 64 + wi];
        unsigned short hv = f2bf_rne(v);
        unsigned short lv = f2bf_rne(v - bf2f(hv));
        t[c_loc][wi] = (unsigned)hv | ((unsigned)lv << 16);
    }
    __syncthreads();
    const int p = tid >> 2, j = tid & 3;
    size_t base = (((size_t)(b * H_ + h) * W_ + wt * 64 + p) << 8) + ct * 64 + j * 16;
    u16x4 hv4[4], lv4[4];
    #pragma unroll
    for (int e = 0; e < 16; ++e) {
        unsigned u = t[j * 16 + e][p];
        hv4[e >> 2][e & 3] = (unsigned short)(u & 0xffffu);
        lv4[e >> 2][e & 3] = (unsigned short)(u >> 16);
    }
    #pragma unroll
    for (int q2 = 0; q2 < 4; ++q2) {
        *(u16x4*)(hi + base + q2 * 4) = hv4[q2];
        *(u16x4*)(lo + base + q2 * 4) = lv4[q2];
    }
}

// ---- staging (per-wave op counts: W slice = 4, x chunk = 3) ----
__device__ __forceinline__ void stage_w2(const unsigned short* __restrict__ wb3,
                                         char* smem, int woff, int sl, int wid, int l) {
    const char* src = (const char*)wb3 + ((size_t)sl << 14);
    #pragma unroll
    for (int j = 0; j < 4; ++j) {
        const int seg = ((j << 2) + wid) << 10;      // (j*4 + wid) * 1024
        __builtin_amdgcn_global_load_lds(
            (const __attribute__((address_space(1))) uint32_t*)(src + seg + l * 16),
            (__attribute__((address_space(3))) uint32_t*)(smem + woff + seg), 16, 0, 0);
    }
    __builtin_amdgcn_sched_barrier(0);
}

__device__ __forceinline__ void stage_x2(const unsigned short* __restrict__ hi_in,
                                         const unsigned short* __restrict__ zb,
                                         char* smem, int xoff, int b, int tr, int tc,
                                         int cq, int wid, int l) {
    const int slot_r = l >> 2, sub = l & 3;
    #pragma unroll
    for (int op = 0; op < 3; ++op) {
        const int sbase = ((op << 2) + wid) << 4;    // 0..176 step 16, wave-uniform
        const int s = sbase + slot_r;                // 0..191 (>=180 -> pad slots)
        const int rr = (s * 3641) >> 16;             // s/18
        const int hc = s - rr * 18;
        const int h = tr * 8 + rr - 1;
        const int w = tc * 16 + hc - 1;
        const unsigned short* src;
        if (s < 180 && (unsigned)h < 128u && (unsigned)w < 128u)
            src = hi_in + (((size_t)((b * 128 + h) * 128 + w)) << 8) + (cq << 5)
                        + ((sub ^ (s & 3)) << 3);    // swizzle folded into global addr
        else
            src = zb + (sub << 3);                   // zero halo / pad
        __builtin_amdgcn_global_load_lds(
            (const __attribute__((address_space(1))) uint32_t*)src,
            (__attribute__((address_space(3))) uint32_t*)(smem + xoff + (sbase << 6)),
            16, 0, 0);
    }
    __builtin_amdgcn_sched_barrier(0);
}

// ---- main step: 512 blocks (16x8 px), 4 waves, 32x32x16 MFMA, 4x2 frags/wave,
//      32-c chunks (72 slices), counted-vmcnt pipeline, 2 blocks/CU,
//      LDS-transpose epilogue for coalesced hi/lo RMW
__global__ __launch_bounds__(256, 2)
void nca_v9(const unsigned short* __restrict__ hi_in,
            const unsigned short* __restrict__ lo_in,
            const unsigned short* __restrict__ wb3,
            const unsigned short* __restrict__ zb,
            const float* __restrict__ mask,
            unsigned short* __restrict__ hi_out,
            unsigned short* __restrict__ lo_out)
{
    extern __shared__ char smem[];
    const int tid = threadIdx.x;
    const int l = tid & 63, wid = tid >> 6;          // 4 waves
    const int wave_o = wid & 1, wave_p = wid >> 1;   // o-half (128 o) x px-half (64 px)
    const int lane31 = l & 31, khalf = l >> 5;
    const int col = l & 15, rowin = (l >> 4) & 1;

    int bid = blockIdx.x;
    const int tc = bid & 7; bid >>= 3;
    const int tr = bid & 15; const int b = bid >> 4;

    // mask bits (9 taps x 2 row-pairs), consumed before staging so vmcnt stays exact
    unsigned mbits = 0;
    #pragma unroll
    for (int k = 0; k < 9; ++k) {
        #pragma unroll
        for (int n = 0; n < 2; ++n) {
            const int h = tr * 8 + wave_p * 4 + n * 2 + rowin;
            const int w = tc * 16 + col;
            unsigned bit = (mask[k * NPIX + h * W_ + w] != 0.f) ? 1u : 0u;
            mbits |= bit << (k * 2 + n);
        }
    }
    __builtin_amdgcn_sched_barrier(0);

    // prologue queue (per wave): W0(4) W1(4) X0(3) X1(3) = 14 ops
    stage_w2(wb3, smem, WOFF,        0, wid, l);
    stage_w2(wb3, smem, WOFF + WSL2, 1, wid, l);
    stage_x2(hi_in, zb, smem, 0,     b, tr, tc, 0, wid, l);
    stage_x2(hi_in, zb, smem, XSZ2,  b, tr, tc, 1, wid, l);

    int sB[2];
    #pragma unroll
    for (int n = 0; n < 2; ++n) sB[n] = (wave_p * 4 + n * 2 + rowin) * 18 + col;
    int abase[4], aswz[4];
    #pragma unroll
    for (int mo = 0; mo < 4; ++mo) {
        int o_l = wave_o * 128 + mo * 32 + lane31;
        abase[mo] = o_l << 6;
        aswz[mo] = o_l & 3;
    }

    f32x16 zv;
    #pragma unroll
    for (int r = 0; r < 16; ++r) zv[r] = 0.f;
    f32x16 acc[4][2];
    #pragma unroll
    for (int mo = 0; mo < 4; ++mo)
        #pragma unroll
        for (int n = 0; n < 2; ++n) acc[mo][n] = zv;

    #pragma unroll 1
    for (int cq = 0; cq < 8; ++cq) {
        const char* xbuf = smem + ((cq & 1) ? XSZ2 : 0);
        #pragma unroll 1
        for (int k = 0; k < 9; ++k) {
            const int sl = cq * 9 + k;
            // per-wave counted waits (ops: W=4, X=3), derived from issue order:
            //  sl==0: need W0+X0 done, X1 in flight -> vmcnt(3)
            //  k<=1 : newer-than-W(sl) = X(3) + W(sl+1)(4) -> vmcnt(7)
            //  else : newer = W(sl+1)(4) -> vmcnt(4);  sl==71 -> vmcnt(0)
            if (sl == 0)       asm volatile("s_waitcnt vmcnt(3)" ::: "memory");
            else if (sl == 71) asm volatile("s_waitcnt vmcnt(0)" ::: "memory");
            else if (k <= 1)   asm volatile("s_waitcnt vmcnt(7)" ::: "memory");
            else               asm volatile("s_waitcnt vmcnt(4)" ::: "memory");
            __builtin_amdgcn_sched_barrier(0);
            __builtin_amdgcn_s_barrier();

            const int dy = (k * 11) >> 5;
            const int dx = k - dy * 3;
            const int doff = dy * 18 + dx;
            const char* wbuf = smem + WOFF + ((sl & 1) ? WSL2 : 0);
            const unsigned mk = mbits >> (k * 2);

            int sx[2];
            #pragma unroll
            for (int n = 0; n < 2; ++n) sx[n] = sB[n] + doff;

            __builtin_amdgcn_s_setprio(1);
            #pragma unroll
            for (int ks = 0; ks < 2; ++ks) {
                const int u = ks * 2 + khalf;
                bf16x8 av[4];
                #pragma unroll
                for (int mo = 0; mo < 4; ++mo)
                    av[mo] = *(const bf16x8*)(wbuf + abase[mo] + ((u ^ aswz[mo]) << 4));
                bf16x8 bv[2];
                #pragma unroll
                for (int n = 0; n < 2; ++n) {
                    i32x4 braw = *(const i32x4*)(xbuf + (sx[n] << 6) + ((u ^ (sx[n] & 3)) << 4));
                    const int mm = -(int)((mk >> n) & 1u);
                    #pragma unroll
                    for (int w4 = 0; w4 < 4; ++w4) braw[w4] &= mm;   // binary mask, exact
                    bv[n] = __builtin_bit_cast(bf16x8, braw);
                }
                #pragma unroll
                for (int mo = 0; mo < 4; ++mo)
                    #pragma unroll
                    for (int n = 0; n < 2; ++n)
                        acc[mo][n] = __builtin_amdgcn_mfma_f32_32x32x16_bf16(av[mo], bv[n], acc[mo][n], 0, 0, 0);
            }
            __builtin_amdgcn_s_setprio(0);

            asm volatile("" ::: "memory");
            __builtin_amdgcn_s_barrier();
            if (sl + 2 < 72)
                stage_w2(wb3, smem, WOFF + ((sl & 1) ? WSL2 : 0), sl + 2, wid, l);
            if (k == 8 && cq < 6)
                stage_x2(hi_in, zb, smem, (cq & 1) ? XSZ2 : 0, b, tr, tc, cq + 2, wid, l);
        }
    }

    // ---- epilogue: 2 phases of 64 px (n index); LDS transpose (64 KB) ->
    //      fully-coalesced 16B/lane hi/lo read-modify-write
    __syncthreads();
    #pragma unroll 1
    for (int n = 0; n < 2; ++n) {
        // write: f32 deltas at [pl][ch], 16-B units XOR-swizzled by (pl&7)
        const int pl = (wave_p * 2 + rowin) * 16 + col;          // 0..63
        #pragma unroll
        for (int mo = 0; mo < 4; ++mo)
            #pragma unroll
            for (int rq = 0; rq < 4; ++rq) {
                const int u = wave_o * 32 + mo * 8 + rq * 2 + khalf;  // 4-ch unit
                f32x4 v;
                v[0] = acc[mo][n][rq * 4 + 0];
                v[1] = acc[mo][n][rq * 4 + 1];
                v[2] = acc[mo][n][rq * 4 + 2];
                v[3] = acc[mo][n][rq * 4 + 3];
                *(f32x4*)(smem + pl * 1024 + ((u ^ (pl & 7)) << 4)) = v;
            }
        __syncthreads();
        // read: 4 threads/px, 16B granules, contiguous 64B per px per j
        {
            const int pl2 = tid >> 2, q = tid & 3;
            const int pr = pl2 >> 4;
            const int h = tr * 8 + (pr >> 1) * 4 + n * 2 + (pr & 1);
            const int w = tc * 16 + (pl2 & 15);
            const size_t pixbase = ((size_t)((b * 128 + h) * 128 + w)) << 8;
            #pragma unroll
            for (int j = 0; j < 8; ++j) {
                const int u0 = q * 2 + j * 8;
                const f32x4 d0 = *(const f32x4*)(smem + pl2 * 1024 + ((u0 ^ (pl2 & 7)) << 4));
                const f32x4 d1 = *(const f32x4*)(smem + pl2 * 1024 + (((u0 + 1) ^ (pl2 & 7)) << 4));
                const size_t a2 = pixbase + (size_t)u0 * 4;
                const u16x8 h8 = *(const u16x8*)(hi_in + a2);
                const u16x8 l8 = *(const u16x8*)(lo_in + a2);
                u16x8 ho, lo2;
                #pragma unroll
                for (int r = 0; r < 8; ++r) {
                    const float dd = (r < 4) ? d0[r] : d1[r - 4];
                    const float xv = bf2f(h8[r]) + bf2f(l8[r]);
                    const float xn = xv + dd / (1.f + fabsf(dd));
                    ho[r] = f2bf_rne(xn);
                    lo2[r] = f2bf_rne(xn - bf2f(ho[r]));
                }
                *(u16x8*)(hi_out + a2) = ho;
                *(u16x8*)(lo_out + a2) = lo2;
            }
        }
        __syncthreads();
    }
}

// ---- final: channel-last hi/lo shadows -> fp32 (B,C,H,W) via LDS transpose
__global__ __launch_bounds__(256)
void shadows_to_f32(const unsigned short* __restrict__ hi,
                    const unsigned short* __restrict__ lo,
                    float* __restrict__ out)
{
    __shared__ float t[64][132];
    int bid = blockIdx.x;
    const int ct = bid & 3;  bid >>= 2;
    const int h  = bid & 127; const int b = bid >> 7;
    const int tid = threadIdx.x;
    #pragma unroll
    for (int pass = 0; pass < 8; ++pass) {
        const int w = pass * 16 + (tid >> 4);
        const int c0 = (tid & 15) * 4;
        const size_t base = (((size_t)((b * 128 + h) * 128 + w)) << 8) + ct * 64 + c0;
        const u16x4 hv = *(const u16x4*)(hi + base);
        const u16x4 lv = *(const u16x4*)(lo + base);
        #pragma unroll
        for (int e = 0; e < 4; ++e) t[c0 + e][w] = bf2f(hv[e]) + bf2f(lv[e]);
    }
    __syncthreads();
    #pragma unroll
    for (int pass = 0; pass < 8; ++pass) {
        const int c = pass * 8 + (tid >> 5);
        const int w = (tid & 31) * 4;
        float4 v = make_float4(t[c][w], t[c][w + 1], t[c][w + 2], t[c][w + 3]);
        *(float4*)(out + ((size_t)(b * C_ + ct * 64 + c) * H_ + h) * W_ + w) = v;
    }
}

// ================= fp32 fallback (only if ws too small) =================
#define OT 64
#define TR 4
#define TC 16
#define CKC 16
__global__ __launch_bounds__(256)
void nca_step_f32(const float* __restrict__ xin, const float* __restrict__ wg,
                  const float* __restrict__ mask, float* __restrict__ xout)
{
    __shared__ __align__(16) float w_s[CKC][9][OT];
    __shared__ __align__(16) float x_s[CKC][TR + 2][20];
    const int tid = threadIdx.x;
    int bt = blockIdx.x;
    const int col_tile = bt & 7;  bt >>= 3;
    const int row_tile = bt & 31; bt >>= 5;
    const int ot = bt & 3;        const int b = bt >> 2;
    const int gr0 = row_tile * TR, gc0 = col_tile * TC, o_base = ot * OT;
    const int og = tid >> 4, pg = tid & 15;
    const int prow = pg >> 2, pcol4 = (pg & 3) * 4;
    const int orow = gr0 + prow, ocol0 = gc0 + pcol4;
    float mask_r[9][4];
#pragma unroll
    for (int k = 0; k < 9; ++k)
#pragma unroll
        for (int j = 0; j < 4; ++j)
            mask_r[k][j] = mask[k * NPIX + orow * W_ + (ocol0 + j)];
    float acc[4][4];
#pragma unroll
    for (int a = 0; a < 4; ++a)
#pragma unroll
        for (int j = 0; j < 4; ++j) acc[a][j] = 0.f;
    for (int chunk = 0; chunk < C_ / CKC; ++chunk) {
        const int c0 = chunk * CKC;
#pragma unroll
        for (int i = 0; i < 36; ++i) {
            const int flat = i * 256 + tid;
            const int o_l = flat / 144;
            const int r = flat - o_l * 144;
            const int c_l = r / 9;
            const int kk = r - c_l * 9;
            w_s[c_l][kk][o_l] = wg[(o_base + o_l) * (C_ * 9) + (c0 + c_l) * 9 + kk];
        }
#pragma unroll
        for (int i = 0; i < 7; ++i) {
            const int flat = i * 256 + tid;
            if (flat < CKC * 108) {
                const int c_l = flat / 108;
                const int r = flat - c_l * 108;
                const int row = r / 18, colx = r - row * 18;
                const int grow = gr0 - 1 + row, gcol = gc0 - 1 + colx;
                float v = 0.f;
                if ((unsigned)grow < (unsigned)H_ && (unsigned)gcol < (unsigned)W_)
                    v = xin[((b * C_ + c0 + c_l) * H_ + grow) * W_ + gcol];
                x_s[c_l][row][colx] = v;
            }
        }
        __syncthreads();
#pragma unroll
        for (int dyy = 0; dyy < 3; ++dyy) {
            float acck[3][4][4];
#pragma unroll
            for (int dxx = 0; dxx < 3; ++dxx)
#pragma unroll
                for (int a = 0; a < 4; ++a)
#pragma unroll
                    for (int j = 0; j < 4; ++j) acck[dxx][a][j] = 0.f;
#pragma unroll 4
            for (int c = 0; c < CKC; ++c) {
                const float4 xv4 = *(const float4*)&x_s[c][prow + dyy][pcol4];
                const float2 xv2 = *(const float2*)&x_s[c][prow + dyy][pcol4 + 4];
                const float xv[6] = {xv4.x, xv4.y, xv4.z, xv4.w, xv2.x, xv2.y};
#pragma unroll
                for (int dxx = 0; dxx < 3; ++dxx) {
                    const float4 wv = *(const float4*)&w_s[c][dyy * 3 + dxx][og * 4];
                    const float wa[4] = {wv.x, wv.y, wv.z, wv.w};
#pragma unroll
                    for (int a = 0; a < 4; ++a)
#pragma unroll
                        for (int j = 0; j < 4; ++j)
                            acck[dxx][a][j] = fmaf(wa[a], xv[j + dxx], acck[dxx][a][j]);
                }
            }
#pragma unroll
            for (int dxx = 0; dxx < 3; ++dxx) {
                const int k = dyy * 3 + dxx;
#pragma unroll
                for (int a = 0; a < 4; ++a)
#pragma unroll
                    for (int j = 0; j < 4; ++j)
                        acc[a][j] = fmaf(mask_r[k][j], acck[dxx][a][j], acc[a][j]);
            }
        }
        __syncthreads();
    }
#pragma unroll
    for (int a = 0; a < 4; ++a) {
        const int o = o_base + og * 4 + a;
#pragma unroll
        for (int j = 0; j < 4; ++j) {
            const int idx = ((b * C_ + o) * H_ + orow) * W_ + (ocol0 + j);
            const float d = acc[a][j];
            xout[idx] = xin[idx] + d / (1.0f + fabsf(d));
        }
    }
}

extern "C" void kernel_launch(void* const* d_in, const int* in_sizes, int n_in,
                              void* d_out, int out_size, void* d_ws, size_t ws_size,
                              hipStream_t stream) {
    const float* retina = (const float*)d_in[0];
    const float* wg     = (const float*)d_in[1];
    const float* mask   = (const float*)d_in[2];
    float* out = (float*)d_out;

    const size_t need = 0x4200000;   // wb3+zb (2M) + hiA/loA (2x32M)

    if (ws_size >= need) {
        unsigned short* wb3 = (unsigned short*)d_ws;
        unsigned short* zb  = (unsigned short*)((char*)d_ws + 0x120000);
        unsigned short* hiA = (unsigned short*)((char*)d_ws + 0x200000);
        unsigned short* loA = (unsigned short*)((char*)d_ws + 0x2200000);
        unsigned short* hiB = (unsigned short*)d_out;              // first 32 MB of out
        unsigned short* loB = hiB + (size_t)B_ * NPIX * C_;        // second 32 MB

        hipFuncSetAttribute((const void*)nca_v9,
                            hipFuncAttributeMaxDynamicSharedMemorySize, LDS_TOTAL);

        prep_w3<<<2305, 256, 0, stream>>>(wg, wb3, zb);
        prep_split<<<4096, 256, 0, stream>>>(retina, hiB, loB);    // state starts in B (d_out)

        // B->A->B->A->B->A : final state lands in ws, then transpose into d_out
        nca_v9<<<512, 256, LDS_TOTAL, stream>>>(hiB, loB, wb3, zb, mask, hiA, loA);
        nca_v9<<<512, 256, LDS_TOTAL, stream>>>(hiA, loA, wb3, zb, mask, hiB, loB);
        nca_v9<<<512, 256, LDS_TOTAL, stream>>>(hiB, loB, wb3, zb, mask, hiA, loA);
        nca_v9<<<512, 256, LDS_TOTAL, stream>>>(hiA, loA, wb3, zb, mask, hiB, loB);
        nca_v9<<<512, 256, LDS_TOTAL, stream>>>(hiB, loB, wb3, zb, mask, hiA, loA);
        shadows_to_f32<<<2048, 256, 0, stream>>>(hiA, loA, out);
    } else {
        float* ws = (float*)d_ws;
        const int nblocks = B_ * (C_ / OT) * (H_ / TR) * (W_ / TC);
        const float* src = retina;
        float* dsts[5] = {out, ws, out, ws, out};
        for (int s = 0; s < 5; ++s) {
            nca_step_f32<<<dim3(nblocks), dim3(256), 0, stream>>>(src, wg, mask, dsts[s]);
            src = dsts[s];
        }
    }
}

// Round 9
// 585.224 us; speedup vs baseline: 1.6186x; 1.1037x over previous
//
#include <hip/hip_runtime.h>
#include <math.h>
#include <stdint.h>

#define B_ 4
#define C_ 256
#define H_ 128
#define W_ 128
#define NPIX (H_*W_)

typedef short bf16x8 __attribute__((ext_vector_type(8)));
typedef int   i32x4  __attribute__((ext_vector_type(4)));
typedef float f32x4  __attribute__((ext_vector_type(4)));
typedef float f32x16 __attribute__((ext_vector_type(16)));
typedef unsigned short u16x4 __attribute__((ext_vector_type(4)));

// ---- LDS map (2 blocks/CU): x halo single buffer + W double buffer ----
// x: 352 slots (18x18 halo = 324 used + pad) * 128 B (64 c bf16, XOR-swizzled)
// W: 16 KB slice (128 o * 64 c, 128-B rows, XOR o&7), double-buffered
// epilogue reuses [0, 64 KB) as 128 px * 512 B delta transpose buffer
#define XSZ   45056
#define WOFF  XSZ
#define WSL   16384
#define LDS_TOTAL (WOFF + 2*WSL)   // 77824 <= 81920 -> 2 blocks/CU

__device__ __forceinline__ unsigned short f2bf_rne(float v) {
    uint32_t b = __float_as_uint(v);
    return (unsigned short)((b + 0x7fff + ((b >> 16) & 1)) >> 16);
}
__device__ __forceinline__ float bf2f(unsigned short h) {
    return __uint_as_float(((uint32_t)h) << 16);
}

// ---- prep: W -> wb4[oh][sl][o_loc 128][u' 8][e 8], sl = qt*9+k,
//      u' = u ^ (o_loc&7), c = qt*64 + u*8 + e, o = oh*128 + o_loc
__global__ __launch_bounds__(256)
void prep_w4(const float* __restrict__ wg, unsigned short* __restrict__ wb4,
             unsigned short* __restrict__ zb) {
    if (blockIdx.x == 2304) { if (threadIdx.x < 128) zb[threadIdx.x] = 0; return; }
    int f = blockIdx.x * 256 + threadIdx.x;          // < 589824
    int s2 = f >> 13;                                 // oh*36 + sl
    int r = f & 8191;
    int o_loc = r >> 6;
    int t = r & 63;
    int up = t >> 3, e = t & 7;
    int oh = s2 / 36, sl = s2 - oh * 36;
    int qt = sl / 9, k = sl - qt * 9;
    int u = up ^ (o_loc & 7);
    int c = qt * 64 + u * 8 + e;
    int o = oh * 128 + o_loc;
    wb4[f] = f2bf_rne(wg[(o * C_ + c) * 9 + k]);
}

// ---- prep: retina fp32 (B,C,H,W) -> channel-last hi/lo bf16 shadows (B,H,W,C)
__global__ __launch_bounds__(256)
void prep_split(const float* __restrict__ retina, unsigned short* __restrict__ hi,
                unsigned short* __restrict__ lo) {
    __shared__ unsigned int t[64][65];
    int bid = blockIdx.x;
    const int wt = bid & 1;        bid >>= 1;
    const int h  = bid & 127;      bid >>= 7;
    const int ct = bid & 3;        const int b = bid >> 2;
    const int tid = threadIdx.x;
    const int ci4 = tid >> 6, wi = tid & 63;
    #pragma unroll
    for (int cc = 0; cc < 16; ++cc) {
        int c_loc = cc * 4 + ci4;
        float v = retina[((size_t)(b * C_ + ct * 64 + c_loc) * H_ + h) * W_ + wt * 64 + wi];
        unsigned short hv = f2bf_rne(v);
        unsigned short lv = f2bf_rne(v - bf2f(hv));
        t[c_loc][wi] = (unsigned)hv | ((unsigned)lv << 16);
    }
    __syncthreads();
    const int p = tid >> 2, j = tid & 3;
    size_t base = (((size_t)(b * H_ + h) * W_ + wt * 64 + p) << 8) + ct * 64 + j * 16;
    u16x4 hv4[4], lv4[4];
    #pragma unroll
    for (int e = 0; e < 16; ++e) {
        unsigned u = t[j * 16 + e][p];
        hv4[e >> 2][e & 3] = (unsigned short)(u & 0xffffu);
        lv4[e >> 2][e & 3] = (unsigned short)(u >> 16);
    }
    #pragma unroll
    for (int q2 = 0; q2 < 4; ++q2) {
        *(u16x4*)(hi + base + q2 * 4) = hv4[q2];
        *(u16x4*)(lo + base + q2 * 4) = lv4[q2];
    }
}

// ---- staging: W slice = 4 ops/wave; x 64-c quarter = 11 ops/wave (exact) ----
__device__ __forceinline__ void stage_w(const unsigned short* __restrict__ wb4,
                                        char* smem, int woff, int oh, int sl,
                                        int wid, int l) {
    const char* src = (const char*)wb4 + ((size_t)(oh * 36 + sl) << 14);
    #pragma unroll
    for (int j = 0; j < 4; ++j) {
        const int seg = ((j << 2) + wid) << 10;      // (j*4 + wid) * 1024
        __builtin_amdgcn_global_load_lds(
            (const __attribute__((address_space(1))) uint32_t*)(src + seg + l * 16),
            (__attribute__((address_space(3))) uint32_t*)(smem + woff + seg), 16, 0, 0);
    }
    __builtin_amdgcn_sched_barrier(0);
}

__device__ __forceinline__ void stage_x(const unsigned short* __restrict__ hi_in,
                                        const unsigned short* __restrict__ zb,
                                        char* smem, int b, int tr, int tc,
                                        int qt, int wid, int l) {
    const int slot_r = l >> 3, sub = l & 7;
    #pragma unroll
    for (int op = 0; op < 11; ++op) {
        const int sbase = (op << 5) + (wid << 3);    // [0,352) step 8, no overlap
        const int s = sbase + slot_r;
        const int rr = (s * 3641) >> 16;             // s/18 valid for s<=383
        const int hc = s - rr * 18;
        const int h = tr * 16 + rr - 1;
        const int w = tc * 16 + hc - 1;
        const unsigned short* src;
        if (s < 324 && (unsigned)h < 128u && (unsigned)w < 128u)
            src = hi_in + (((size_t)((b * 128 + h) * 128 + w)) << 8) + (qt << 6)
                        + ((sub ^ (s & 7)) << 3);    // swizzle folded into global addr
        else
            src = zb + (sub << 3);                   // zero halo / pad slots
        __builtin_amdgcn_global_load_lds(
            (const __attribute__((address_space(1))) uint32_t*)src,
            (__attribute__((address_space(3))) uint32_t*)(smem + (sbase << 7)),
            16, 0, 0);
    }
    __builtin_amdgcn_sched_barrier(0);
}

// ---- main step: 512 blocks (128 o x 16x16 px), 4 waves, 32x32x16 MFMA,
//      mo2 x n4 frags/wave, x single-buffer + W dbuf, uniform vmcnt(4),
//      2 blocks/CU, conflict-free LDS-transpose epilogue
__global__ __launch_bounds__(256, 2)
void nca_v10(const unsigned short* __restrict__ hi_in,
             const unsigned short* __restrict__ lo_in,
             const unsigned short* __restrict__ wb4,
             const unsigned short* __restrict__ zb,
             const float* __restrict__ mask,
             unsigned short* __restrict__ hi_out,
             unsigned short* __restrict__ lo_out)
{
    extern __shared__ char smem[];
    const int tid = threadIdx.x;
    const int l = tid & 63, wid = tid >> 6;          // 4 waves
    const int wave_o = wid & 1, wp = wid >> 1;       // 64-o half x 8-row half
    const int lane31 = l & 31, khalf = l >> 5;
    const int col = l & 15, rowin = (l >> 4) & 1;

    int bid = blockIdx.x;
    const int oh = bid & 1; bid >>= 1;
    const int tc = bid & 7; bid >>= 3;
    const int tr = bid & 7; const int b = bid >> 3;

    // mask bits (9 taps x 4 row-pairs) before staging so vmcnt counts stay exact
    unsigned long long mbits = 0ull;
    #pragma unroll
    for (int k = 0; k < 9; ++k) {
        #pragma unroll
        for (int n = 0; n < 4; ++n) {
            const int h = tr * 16 + wp * 8 + n * 2 + rowin;
            const int w = tc * 16 + col;
            unsigned long long bit = (mask[k * NPIX + h * W_ + w] != 0.f) ? 1ull : 0ull;
            mbits |= bit << (k * 4 + n);
        }
    }
    __builtin_amdgcn_sched_barrier(0);

    // prologue queue (per wave): X0(11), W0(4), W1(4)  -> steady vmcnt(4)
    stage_x(hi_in, zb, smem, b, tr, tc, 0, wid, l);
    stage_w(wb4, smem, WOFF,       oh, 0, wid, l);
    stage_w(wb4, smem, WOFF + WSL, oh, 1, wid, l);

    int sB[4];
    #pragma unroll
    for (int n = 0; n < 4; ++n) sB[n] = (wp * 8 + n * 2 + rowin) * 18 + col;
    int abase[2], aswz[2];
    #pragma unroll
    for (int mo = 0; mo < 2; ++mo) {
        int o_l = wave_o * 64 + mo * 32 + lane31;
        abase[mo] = o_l << 7;
        aswz[mo] = o_l & 7;
    }

    f32x16 zv;
    #pragma unroll
    for (int r = 0; r < 16; ++r) zv[r] = 0.f;
    f32x16 acc[2][4];
    #pragma unroll
    for (int mo = 0; mo < 2; ++mo)
        #pragma unroll
        for (int n = 0; n < 4; ++n) acc[mo][n] = zv;

    #pragma unroll 1
    for (int qt = 0; qt < 4; ++qt) {
        #pragma unroll 1
        for (int k = 0; k < 9; ++k) {
            const int sl = qt * 9 + k;
            if (sl == 35) asm volatile("s_waitcnt vmcnt(0)" ::: "memory");
            else          asm volatile("s_waitcnt vmcnt(4)" ::: "memory");
            __builtin_amdgcn_sched_barrier(0);
            __builtin_amdgcn_s_barrier();

            const int dy = (k * 11) >> 5;
            const int dx = k - dy * 3;
            const int doff = dy * 18 + dx;
            const char* wbuf = smem + WOFF + ((sl & 1) ? WSL : 0);
            const unsigned mk = (unsigned)(mbits >> (k * 4));

            int sx[4];
            #pragma unroll
            for (int n = 0; n < 4; ++n) sx[n] = sB[n] + doff;

            __builtin_amdgcn_s_setprio(1);
            #pragma unroll
            for (int ks = 0; ks < 4; ++ks) {
                const int u = ks * 2 + khalf;
                bf16x8 av[2];
                #pragma unroll
                for (int mo = 0; mo < 2; ++mo)
                    av[mo] = *(const bf16x8*)(wbuf + abase[mo] + ((u ^ aswz[mo]) << 4));
                bf16x8 bv[4];
                #pragma unroll
                for (int n = 0; n < 4; ++n) {
                    i32x4 braw = *(const i32x4*)(smem + (sx[n] << 7) + ((u ^ (sx[n] & 7)) << 4));
                    const int mm = -(int)((mk >> n) & 1u);
                    #pragma unroll
                    for (int w4 = 0; w4 < 4; ++w4) braw[w4] &= mm;   // binary mask, exact
                    bv[n] = __builtin_bit_cast(bf16x8, braw);
                }
                #pragma unroll
                for (int mo = 0; mo < 2; ++mo)
                    #pragma unroll
                    for (int n = 0; n < 4; ++n)
                        acc[mo][n] = __builtin_amdgcn_mfma_f32_32x32x16_bf16(av[mo], bv[n], acc[mo][n], 0, 0, 0);
            }
            __builtin_amdgcn_s_setprio(0);

            asm volatile("" ::: "memory");
            __builtin_amdgcn_s_barrier();
            // x restage first (keeps W newest -> uniform vmcnt(4) works)
            if (k == 8 && qt < 3)
                stage_x(hi_in, zb, smem, b, tr, tc, qt + 1, wid, l);
            if (sl + 2 < 36)
                stage_w(wb4, smem, WOFF + ((sl & 1) ? WSL : 0), oh, sl + 2, wid, l);
        }
    }

    // ---- epilogue: 2 phases x 128 px; LDS layout addr(px,u) =
    //      px*512 + (u>>3)*128 + (((u&7)^(u>>3)^(px&7))<<4)  -> <=2-way both phases
    __syncthreads();
    #pragma unroll 1
    for (int ph = 0; ph < 2; ++ph) {
        #pragma unroll
        for (int n1 = 0; n1 < 2; ++n1) {
            const int n = ph * 2 + n1;
            const int pxp = (wp * 4 + n1 * 2 + ((l & 31) >> 4)) * 16 + col;  // 0..127
            #pragma unroll
            for (int mo = 0; mo < 2; ++mo)
                #pragma unroll
                for (int rq = 0; rq < 4; ++rq) {
                    const int u = wave_o * 16 + mo * 8 + rq * 2 + khalf;      // 0..31
                    f32x4 v;
                    v[0] = acc[mo][n][rq * 4 + 0];
                    v[1] = acc[mo][n][rq * 4 + 1];
                    v[2] = acc[mo][n][rq * 4 + 2];
                    v[3] = acc[mo][n][rq * 4 + 3];
                    *(f32x4*)(smem + pxp * 512 + ((u >> 3) << 7)
                              + ((((u & 7) ^ (u >> 3) ^ (pxp & 7))) << 4)) = v;
                }
        }
        __syncthreads();
        #pragma unroll 2
        for (int it = 0; it < 16; ++it) {
            const int pxp = it * 8 + wid * 2 + (l >> 5);
            const int u = l & 31;
            const f32x4 d4 = *(const f32x4*)(smem + pxp * 512 + ((u >> 3) << 7)
                                             + ((((u & 7) ^ (u >> 3) ^ (pxp & 7))) << 4));
            const int rp = pxp >> 4;
            const int h = tr * 16 + (rp >> 2) * 8 + ph * 4 + (rp & 3);
            const int w = tc * 16 + (pxp & 15);
            const size_t a2 = (((size_t)((b * 128 + h) * 128 + w)) << 8)
                              + (oh << 7) + (size_t)u * 4;
            const u16x4 h4 = *(const u16x4*)(hi_in + a2);
            const u16x4 l4 = *(const u16x4*)(lo_in + a2);
            u16x4 ho, lo2;
            #pragma unroll
            for (int r = 0; r < 4; ++r) {
                const float xv = bf2f(h4[r]) + bf2f(l4[r]);
                const float d = d4[r];
                const float xn = xv + d / (1.f + fabsf(d));
                ho[r] = f2bf_rne(xn);
                lo2[r] = f2bf_rne(xn - bf2f(ho[r]));
            }
            *(u16x4*)(hi_out + a2) = ho;
            *(u16x4*)(lo_out + a2) = lo2;
        }
        if (ph == 0) __syncthreads();
    }
}

// ---- final: channel-last hi/lo shadows -> fp32 (B,C,H,W) via LDS transpose
__global__ __launch_bounds__(256)
void shadows_to_f32(const unsigned short* __restrict__ hi,
                    const unsigned short* __restrict__ lo,
                    float* __restrict__ out)
{
    __shared__ float t[64][132];
    int bid = blockIdx.x;
    const int ct = bid & 3;  bid >>= 2;
    const int h  = bid & 127; const int b = bid >> 7;
    const int tid = threadIdx.x;
    #pragma unroll
    for (int pass = 0; pass < 8; ++pass) {
        const int w = pass * 16 + (tid >> 4);
        const int c0 = (tid & 15) * 4;
        const size_t base = (((size_t)((b * 128 + h) * 128 + w)) << 8) + ct * 64 + c0;
        const u16x4 hv = *(const u16x4*)(hi + base);
        const u16x4 lv = *(const u16x4*)(lo + base);
        #pragma unroll
        for (int e = 0; e < 4; ++e) t[c0 + e][w] = bf2f(hv[e]) + bf2f(lv[e]);
    }
    __syncthreads();
    #pragma unroll
    for (int pass = 0; pass < 8; ++pass) {
        const int c = pass * 8 + (tid >> 5);
        const int w = (tid & 31) * 4;
        float4 v = make_float4(t[c][w], t[c][w + 1], t[c][w + 2], t[c][w + 3]);
        *(float4*)(out + ((size_t)(b * C_ + ct * 64 + c) * H_ + h) * W_ + w) = v;
    }
}

// ================= fp32 fallback (only if ws too small) =================
#define OT 64
#define TR 4
#define TC 16
#define CKC 16
__global__ __launch_bounds__(256)
void nca_step_f32(const float* __restrict__ xin, const float* __restrict__ wg,
                  const float* __restrict__ mask, float* __restrict__ xout)
{
    __shared__ __align__(16) float w_s[CKC][9][OT];
    __shared__ __align__(16) float x_s[CKC][TR + 2][20];
    const int tid = threadIdx.x;
    int bt = blockIdx.x;
    const int col_tile = bt & 7;  bt >>= 3;
    const int row_tile = bt & 31; bt >>= 5;
    const int ot = bt & 3;        const int b = bt >> 2;
    const int gr0 = row_tile * TR, gc0 = col_tile * TC, o_base = ot * OT;
    const int og = tid >> 4, pg = tid & 15;
    const int prow = pg >> 2, pcol4 = (pg & 3) * 4;
    const int orow = gr0 + prow, ocol0 = gc0 + pcol4;
    float mask_r[9][4];
#pragma unroll
    for (int k = 0; k < 9; ++k)
#pragma unroll
        for (int j = 0; j < 4; ++j)
            mask_r[k][j] = mask[k * NPIX + orow * W_ + (ocol0 + j)];
    float acc[4][4];
#pragma unroll
    for (int a = 0; a < 4; ++a)
#pragma unroll
        for (int j = 0; j < 4; ++j) acc[a][j] = 0.f;
    for (int chunk = 0; chunk < C_ / CKC; ++chunk) {
        const int c0 = chunk * CKC;
#pragma unroll
        for (int i = 0; i < 36; ++i) {
            const int flat = i * 256 + tid;
            const int o_l = flat / 144;
            const int r = flat - o_l * 144;
            const int c_l = r / 9;
            const int kk = r - c_l * 9;
            w_s[c_l][kk][o_l] = wg[(o_base + o_l) * (C_ * 9) + (c0 + c_l) * 9 + kk];
        }
#pragma unroll
        for (int i = 0; i < 7; ++i) {
            const int flat = i * 256 + tid;
            if (flat < CKC * 108) {
                const int c_l = flat / 108;
                const int r = flat - c_l * 108;
                const int row = r / 18, colx = r - row * 18;
                const int grow = gr0 - 1 + row, gcol = gc0 - 1 + colx;
                float v = 0.f;
                if ((unsigned)grow < (unsigned)H_ && (unsigned)gcol < (unsigned)W_)
                    v = xin[((b * C_ + c0 + c_l) * H_ + grow) * W_ + gcol];
                x_s[c_l][row][colx] = v;
            }
        }
        __syncthreads();
#pragma unroll
        for (int dyy = 0; dyy < 3; ++dyy) {
            float acck[3][4][4];
#pragma unroll
            for (int dxx = 0; dxx < 3; ++dxx)
#pragma unroll
                for (int a = 0; a < 4; ++a)
#pragma unroll
                    for (int j = 0; j < 4; ++j) acck[dxx][a][j] = 0.f;
#pragma unroll 4
            for (int c = 0; c < CKC; ++c) {
                const float4 xv4 = *(const float4*)&x_s[c][prow + dyy][pcol4];
                const float2 xv2 = *(const float2*)&x_s[c][prow + dyy][pcol4 + 4];
                const float xv[6] = {xv4.x, xv4.y, xv4.z, xv4.w, xv2.x, xv2.y};
#pragma unroll
                for (int dxx = 0; dxx < 3; ++dxx) {
                    const float4 wv = *(const float4*)&w_s[c][dyy * 3 + dxx][og * 4];
                    const float wa[4] = {wv.x, wv.y, wv.z, wv.w};
#pragma unroll
                    for (int a = 0; a < 4; ++a)
#pragma unroll
                        for (int j = 0; j < 4; ++j)
                            acck[dxx][a][j] = fmaf(wa[a], xv[j + dxx], acck[dxx][a][j]);
                }
            }
#pragma unroll
            for (int dxx = 0; dxx < 3; ++dxx) {
                const int k = dyy * 3 + dxx;
#pragma unroll
                for (int a = 0; a < 4; ++a)
#pragma unroll
                    for (int j = 0; j < 4; ++j)
                        acc[a][j] = fmaf(mask_r[k][j], acck[dxx][a][j], acc[a][j]);
            }
        }
        __syncthreads();
    }
#pragma unroll
    for (int a = 0; a < 4; ++a) {
        const int o = o_base + og * 4 + a;
#pragma unroll
        for (int j = 0; j < 4; ++j) {
            const int idx = ((b * C_ + o) * H_ + orow) * W_ + (ocol0 + j);
            const float d = acc[a][j];
            xout[idx] = xin[idx] + d / (1.0f + fabsf(d));
        }
    }
}

extern "C" void kernel_launch(void* const* d_in, const int* in_sizes, int n_in,
                              void* d_out, int out_size, void* d_ws, size_t ws_size,
                              hipStream_t stream) {
    const float* retina = (const float*)d_in[0];
    const float* wg     = (const float*)d_in[1];
    const float* mask   = (const float*)d_in[2];
    float* out = (float*)d_out;

    const size_t need = 0x4200000;   // wb4+zb (2M) + hiA/loA (2x32M)

    if (ws_size >= need) {
        unsigned short* wb4 = (unsigned short*)d_ws;
        unsigned short* zb  = (unsigned short*)((char*)d_ws + 0x120000);
        unsigned short* hiA = (unsigned short*)((char*)d_ws + 0x200000);
        unsigned short* loA = (unsigned short*)((char*)d_ws + 0x2200000);
        unsigned short* hiB = (unsigned short*)d_out;              // first 32 MB of out
        unsigned short* loB = hiB + (size_t)B_ * NPIX * C_;        // second 32 MB

        hipFuncSetAttribute((const void*)nca_v10,
                            hipFuncAttributeMaxDynamicSharedMemorySize, LDS_TOTAL);

        prep_w4<<<2305, 256, 0, stream>>>(wg, wb4, zb);
        prep_split<<<4096, 256, 0, stream>>>(retina, hiB, loB);    // state starts in B (d_out)

        // B->A->B->A->B->A : final state lands in ws, then transpose into d_out
        nca_v10<<<512, 256, LDS_TOTAL, stream>>>(hiB, loB, wb4, zb, mask, hiA, loA);
        nca_v10<<<512, 256, LDS_TOTAL, stream>>>(hiA, loA, wb4, zb, mask, hiB, loB);
        nca_v10<<<512, 256, LDS_TOTAL, stream>>>(hiB, loB, wb4, zb, mask, hiA, loA);
        nca_v10<<<512, 256, LDS_TOTAL, stream>>>(hiA, loA, wb4, zb, mask, hiB, loB);
        nca_v10<<<512, 256, LDS_TOTAL, stream>>>(hiB, loB, wb4, zb, mask, hiA, loA);
        shadows_to_f32<<<2048, 256, 0, stream>>>(hiA, loA, out);
    } else {
        float* ws = (float*)d_ws;
        const int nblocks = B_ * (C_ / OT) * (H_ / TR) * (W_ / TC);
        const float* src = retina;
        float* dsts[5] = {out, ws, out, ws, out};
        for (int s = 0; s < 5; ++s) {
            nca_step_f32<<<dim3(nblocks), dim3(256), 0, stream>>>(src, wg, mask, dsts[s]);
            src = dsts[s];
        }
    }
}

// Round 10
// 510.438 us; speedup vs baseline: 1.8558x; 1.1465x over previous
//
#include <hip/hip_runtime.h>
#include <math.h>
#include <stdint.h>

#define B_ 4
#define C_ 256
#define H_ 128
#define W_ 128
#define NPIX (H_*W_)

typedef short bf16x8 __attribute__((ext_vector_type(8)));
typedef int   i32x4  __attribute__((ext_vector_type(4)));
typedef float f32x4  __attribute__((ext_vector_type(4)));
typedef float f32x16 __attribute__((ext_vector_type(16)));
typedef unsigned short u16x4 __attribute__((ext_vector_type(4)));

// ---- LDS map ----
// x: 2 buffers x 328 slots x 128 B (18x18 halo, 64-c quarter, XOR-swizzled)
// W: 8 wave-private regions x 2 buffers x 4 KB (64 o x 32 c slice)
// epilogue reuses [0, 128 KB) as 128 px x 1 KB transpose buffer
#define XSZ   41984
#define WREG  (2*XSZ)              // 83968
#define SCR   (WREG + 8*8192)      // 149504 (1 KB dummy-stage scratch)
#define LDS_TOTAL (SCR + 1024)     // 150528

__device__ __forceinline__ unsigned short f2bf_rne(float v) {
    uint32_t b = __float_as_uint(v);
    return (unsigned short)((b + 0x7fff + ((b >> 16) & 1)) >> 16);
}
__device__ __forceinline__ float bf2f(unsigned short h) {
    return __uint_as_float(((uint32_t)h) << 16);
}

// ---- prep: W -> wb5[sl 72][og 4][row 32][v' 8][e 8]  (4 KB per (sl,og))
// sl = qt*18 + k*2 + chalf ; v = (o_loc&1)*4 + u_a, v' = v ^ (row&7),
// o_loc = row*2 + (v>>2); c = qt*64 + chalf*32 + (v&3)*8 + e; o = og*64 + o_loc.
__global__ __launch_bounds__(256)
void prep_w5(const float* __restrict__ wg, unsigned short* __restrict__ wb5,
             unsigned short* __restrict__ zb) {
    if (blockIdx.x == 2304) { if (threadIdx.x < 128) zb[threadIdx.x] = 0; return; }
    int f = blockIdx.x * 256 + threadIdx.x;          // < 589824
    int g = f >> 11;                                  // (sl*4 + og)
    int within = f & 2047;
    int row = within >> 6;
    int t = within & 63;
    int vp = t >> 3, e = t & 7;
    int v = vp ^ (row & 7);
    int o_loc = row * 2 + (v >> 2);
    int ua = v & 3;
    int sl = g >> 2, og = g & 3;
    int qt = sl / 18, j = sl - qt * 18;
    int k = j >> 1, chalf = j & 1;
    int c = qt * 64 + chalf * 32 + ua * 8 + e;
    int o = og * 64 + o_loc;
    wb5[f] = f2bf_rne(wg[(o * C_ + c) * 9 + k]);
}

// ---- prep: retina fp32 (B,C,H,W) -> channel-last hi/lo bf16 shadows (B,H,W,C)
__global__ __launch_bounds__(256)
void prep_split(const float* __restrict__ retina, unsigned short* __restrict__ hi,
                unsigned short* __restrict__ lo) {
    __shared__ unsigned int t[64][65];
    int bid = blockIdx.x;
    const int wt = bid & 1;        bid >>= 1;
    const int h  = bid & 127;      bid >>= 7;
    const int ct = bid & 3;        const int b = bid >> 2;
    const int tid = threadIdx.x;
    const int ci4 = tid >> 6, wi = tid & 63;
    #pragma unroll
    for (int cc = 0; cc < 16; ++cc) {
        int c_loc = cc * 4 + ci4;
        float v = retina[((size_t)(b * C_ + ct * 64 + c_loc) * H_ + h) * W_ + wt * 64 + wi];
        unsigned short hv = f2bf_rne(v);
        unsigned short lv = f2bf_rne(v - bf2f(hv));
        t[c_loc][wi] = (unsigned)hv | ((unsigned)lv << 16);
    }
    __syncthreads();
    const int p = tid >> 2, j = tid & 3;
    size_t base = (((size_t)(b * H_ + h) * W_ + wt * 64 + p) << 8) + ct * 64 + j * 16;
    u16x4 hv4[4], lv4[4];
    #pragma unroll
    for (int e = 0; e < 16; ++e) {
        unsigned u = t[j * 16 + e][p];
        hv4[e >> 2][e & 3] = (unsigned short)(u & 0xffffu);
        lv4[e >> 2][e & 3] = (unsigned short)(u >> 16);
    }
    #pragma unroll
    for (int q2 = 0; q2 < 4; ++q2) {
        *(u16x4*)(hi + base + q2 * 4) = hv4[q2];
        *(u16x4*)(lo + base + q2 * 4) = lv4[q2];
    }
}

// ---- wave-private W stage: 4 glds ops, guarded only by this wave's vmcnt ----
__device__ __forceinline__ void stage_wv(const unsigned short* __restrict__ wb5,
                                         char* smem, int og, int wid, int sl, int l) {
    const char* src = (const char*)wb5 + ((size_t)(sl * 4 + og) << 12);
    char* dst = smem + WREG + (wid << 13) + ((sl & 1) << 12);
    #pragma unroll
    for (int op = 0; op < 4; ++op) {
        __builtin_amdgcn_global_load_lds(
            (const __attribute__((address_space(1))) uint32_t*)(src + (op << 10) + l * 16),
            (__attribute__((address_space(3))) uint32_t*)(dst + (op << 10)), 16, 0, 0);
    }
    __builtin_amdgcn_sched_barrier(0);
}

// ---- cooperative x stage: 6 ops/wave, exact cover, swizzle folded into src ----
__device__ __forceinline__ void stage_x(const unsigned short* __restrict__ hi_in,
                                        const unsigned short* __restrict__ zb,
                                        char* smem, int b, int tr, int tc,
                                        int qt, int wid, int l) {
    const int slot_r = l >> 3, sub = l & 7;
    const int xoff = (qt & 1) ? XSZ : 0;
    #pragma unroll
    for (int op = 0; op < 6; ++op) {
        const int sbase = ((op << 3) + wid) << 3;    // 0..376 step 8, unique
        const int s = sbase + slot_r;
        const int rr = (s * 3641) >> 16;             // s/18 for s<=383
        const int hc = s - rr * 18;
        const int h = tr * 16 + rr - 1;
        const int w = tc * 16 + hc - 1;
        const unsigned short* src;
        int dst;
        if (sbase < 328) {
            dst = xoff + (sbase << 7);
            if (s < 324 && (unsigned)h < 128u && (unsigned)w < 128u)
                src = hi_in + (((size_t)((b * 128 + h) * 128 + w)) << 8) + (qt << 6)
                            + ((sub ^ (s & 7)) << 3);
            else
                src = zb + (sub << 3);
        } else {
            dst = SCR;
            src = zb + (sub << 3);
        }
        __builtin_amdgcn_global_load_lds(
            (const __attribute__((address_space(1))) uint32_t*)src,
            (__attribute__((address_space(3))) uint32_t*)(smem + dst), 16, 0, 0);
    }
    __builtin_amdgcn_sched_barrier(0);
}

// ---- main step: 256 blocks (256 o x 16x16 px), 8 waves = og4 x ph2,
//      wave-private W pipeline (no per-slice barrier; 3 barriers total),
//      32x32x16 MFMA mo2 x n4, LDS-transpose epilogue
__global__ __launch_bounds__(512, 1)
void nca_v11(const unsigned short* __restrict__ hi_in,
             const unsigned short* __restrict__ lo_in,
             const unsigned short* __restrict__ wb5,
             const unsigned short* __restrict__ zb,
             const float* __restrict__ mask,
             unsigned short* __restrict__ hi_out,
             unsigned short* __restrict__ lo_out)
{
    extern __shared__ char smem[];
    const int tid = threadIdx.x;
    const int l = tid & 63, wid = tid >> 6;          // 8 waves
    const int og = wid & 3, ph = wid >> 2;           // 64-o group x 128-px half
    const int lane31 = l & 31, khalf = l >> 5;
    const int col = l & 15, rowin = (l >> 4) & 1;

    int bid = blockIdx.x;
    const int tc = bid & 7; bid >>= 3;
    const int tr = bid & 7; const int b = bid >> 3;

    // mask bits (9 taps x 4 row-pairs of this wave's px half)
    unsigned long long mbits = 0ull;
    #pragma unroll
    for (int k = 0; k < 9; ++k) {
        #pragma unroll
        for (int n = 0; n < 4; ++n) {
            const int h = tr * 16 + ph * 8 + n * 2 + rowin;
            const int w = tc * 16 + col;
            unsigned long long bit = (mask[k * NPIX + h * W_ + w] != 0.f) ? 1ull : 0ull;
            mbits |= bit << (k * 4 + n);
        }
    }
    __builtin_amdgcn_sched_barrier(0);

    // prologue (per wave): X0(6), W0(4), W1(4)
    stage_x(hi_in, zb, smem, b, tr, tc, 0, wid, l);
    stage_wv(wb5, smem, og, wid, 0, l);
    stage_wv(wb5, smem, og, wid, 1, l);

    int sB[4];
    #pragma unroll
    for (int n = 0; n < 4; ++n) sB[n] = (ph * 8 + n * 2 + rowin) * 18 + col;
    // A addressing: o_loc = mo*32 + lane31; row = o_loc>>1;
    // addr = row*128 + ((((o_loc&1)*4 + u_a) ^ (row&7)) << 4)
    int arow[2], asel[2], aswz[2];
    #pragma unroll
    for (int mo = 0; mo < 2; ++mo) {
        int o_loc = mo * 32 + lane31;
        arow[mo] = (o_loc >> 1) << 7;
        asel[mo] = (o_loc & 1) << 2;
        aswz[mo] = (o_loc >> 1) & 7;
    }

    f32x16 zv;
    #pragma unroll
    for (int r = 0; r < 16; ++r) zv[r] = 0.f;
    f32x16 acc[2][4];
    #pragma unroll
    for (int mo = 0; mo < 2; ++mo)
        #pragma unroll
        for (int n = 0; n < 4; ++n) acc[mo][n] = zv;

    #pragma unroll 1
    for (int sl = 0; sl < 72; ++sl) {
        const int qt = sl / 18;
        const int j = sl - qt * 18;
        const int k = j >> 1, chalf = j & 1;

        // quarter boundary: the ONLY block-wide barriers in the k-loop
        if (j == 0 && qt > 0) {
            asm volatile("s_waitcnt vmcnt(8)" ::: "memory");   // X(qt) retired; 2 W slices in flight
            __builtin_amdgcn_sched_barrier(0);
            __builtin_amdgcn_s_barrier();
        }
        // per-wave counted wait for W(sl): newer ops = W(sl+1) [+X(qt+1) if j==1]
        if (sl == 71)             asm volatile("s_waitcnt vmcnt(0)"  ::: "memory");
        else if (j == 1 && qt < 3) asm volatile("s_waitcnt vmcnt(10)" ::: "memory");
        else                      asm volatile("s_waitcnt vmcnt(4)"  ::: "memory");
        __builtin_amdgcn_sched_barrier(0);

        const int dy = (k * 11) >> 5;
        const int dx = k - dy * 3;
        const int doff = dy * 18 + dx;
        const char* xbuf = smem + ((qt & 1) ? XSZ : 0);
        const char* wbuf = smem + WREG + (wid << 13) + ((sl & 1) << 12);
        const unsigned mk = (unsigned)(mbits >> (k * 4));

        int sx[4];
        #pragma unroll
        for (int n = 0; n < 4; ++n) sx[n] = sB[n] + doff;

        __builtin_amdgcn_s_setprio(1);
        #pragma unroll
        for (int k2 = 0; k2 < 2; ++k2) {
            const int ua = k2 * 2 + khalf;                     // 0..3
            const int ub = chalf * 4 + ua;                     // 0..7
            bf16x8 av[2];
            #pragma unroll
            for (int mo = 0; mo < 2; ++mo)
                av[mo] = *(const bf16x8*)(wbuf + arow[mo] + (((asel[mo] + ua) ^ aswz[mo]) << 4));
            bf16x8 bv[4];
            #pragma unroll
            for (int n = 0; n < 4; ++n) {
                i32x4 braw = *(const i32x4*)(xbuf + (sx[n] << 7) + ((ub ^ (sx[n] & 7)) << 4));
                const int mm = -(int)((mk >> n) & 1u);
                #pragma unroll
                for (int w4 = 0; w4 < 4; ++w4) braw[w4] &= mm;  // binary mask, exact
                bv[n] = __builtin_bit_cast(bf16x8, braw);
            }
            #pragma unroll
            for (int mo = 0; mo < 2; ++mo)
                #pragma unroll
                for (int n = 0; n < 4; ++n)
                    acc[mo][n] = __builtin_amdgcn_mfma_f32_32x32x16_bf16(av[mo], bv[n], acc[mo][n], 0, 0, 0);
        }
        __builtin_amdgcn_s_setprio(0);

        __builtin_amdgcn_sched_barrier(0);
        // prefetches: x for qt+1 early in the quarter; W depth-2 pipeline
        if (j == 0 && qt < 3)
            stage_x(hi_in, zb, smem, b, tr, tc, qt + 1, wid, l);
        if (sl + 2 < 72)
            stage_wv(wb5, smem, og, wid, sl + 2, l);
    }

    // ---- epilogue: 2 phases x 128 px; LDS transpose -> coalesced hi/lo RMW
    __syncthreads();
    #pragma unroll 1
    for (int f = 0; f < 2; ++f) {
        if (ph == f) {
            #pragma unroll
            for (int n = 0; n < 4; ++n) {
                const int pl = (n * 2 + rowin) * 16 + col;                // 0..127
                #pragma unroll
                for (int mo = 0; mo < 2; ++mo)
                    #pragma unroll
                    for (int rq = 0; rq < 4; ++rq) {
                        const int u = og * 16 + mo * 8 + rq * 2 + khalf;  // 0..63
                        f32x4 v;
                        v[0] = acc[mo][n][rq * 4 + 0];
                        v[1] = acc[mo][n][rq * 4 + 1];
                        v[2] = acc[mo][n][rq * 4 + 2];
                        v[3] = acc[mo][n][rq * 4 + 3];
                        *(f32x4*)(smem + pl * 1024 + ((u ^ (pl & 7)) << 4)) = v;
                    }
            }
        }
        __syncthreads();
        #pragma unroll 2
        for (int it = 0; it < 16; ++it) {
            const int pl = it * 8 + wid;                 // pl & 7 == wid
            const int h = tr * 16 + f * 8 + (pl >> 4);
            const int w = tc * 16 + (pl & 15);
            const f32x4 d4 = *(const f32x4*)(smem + pl * 1024 + ((l ^ wid) << 4));
            const size_t base = (((size_t)((b * 128 + h) * 128 + w)) << 8) + l * 4;
            const u16x4 h4 = *(const u16x4*)(hi_in + base);
            const u16x4 l4 = *(const u16x4*)(lo_in + base);
            u16x4 ho, lo2;
            #pragma unroll
            for (int r = 0; r < 4; ++r) {
                const float xv = bf2f(h4[r]) + bf2f(l4[r]);
                const float d = d4[r];
                const float xn = xv + d / (1.f + fabsf(d));
                ho[r] = f2bf_rne(xn);
                lo2[r] = f2bf_rne(xn - bf2f(ho[r]));
            }
            *(u16x4*)(hi_out + base) = ho;
            *(u16x4*)(lo_out + base) = lo2;
        }
        if (f == 0) __syncthreads();
    }
}

// ---- final: channel-last hi/lo shadows -> fp32 (B,C,H,W) via LDS transpose
__global__ __launch_bounds__(256)
void shadows_to_f32(const unsigned short* __restrict__ hi,
                    const unsigned short* __restrict__ lo,
                    float* __restrict__ out)
{
    __shared__ float t[64][132];
    int bid = blockIdx.x;
    const int ct = bid & 3;  bid >>= 2;
    const int h  = bid & 127; const int b = bid >> 7;
    const int tid = threadIdx.x;
    #pragma unroll
    for (int pass = 0; pass < 8; ++pass) {
        const int w = pass * 16 + (tid >> 4);
        const int c0 = (tid & 15) * 4;
        const size_t base = (((size_t)((b * 128 + h) * 128 + w)) << 8) + ct * 64 + c0;
        const u16x4 hv = *(const u16x4*)(hi + base);
        const u16x4 lv = *(const u16x4*)(lo + base);
        #pragma unroll
        for (int e = 0; e < 4; ++e) t[c0 + e][w] = bf2f(hv[e]) + bf2f(lv[e]);
    }
    __syncthreads();
    #pragma unroll
    for (int pass = 0; pass < 8; ++pass) {
        const int c = pass * 8 + (tid >> 5);
        const int w = (tid & 31) * 4;
        float4 v = make_float4(t[c][w], t[c][w + 1], t[c][w + 2], t[c][w + 3]);
        *(float4*)(out + ((size_t)(b * C_ + ct * 64 + c) * H_ + h) * W_ + w) = v;
    }
}

// ================= fp32 fallback (only if ws too small) =================
#define OT 64
#define TR 4
#define TC 16
#define CKC 16
__global__ __launch_bounds__(256)
void nca_step_f32(const float* __restrict__ xin, const float* __restrict__ wg,
                  const float* __restrict__ mask, float* __restrict__ xout)
{
    __shared__ __align__(16) float w_s[CKC][9][OT];
    __shared__ __align__(16) float x_s[CKC][TR + 2][20];
    const int tid = threadIdx.x;
    int bt = blockIdx.x;
    const int col_tile = bt & 7;  bt >>= 3;
    const int row_tile = bt & 31; bt >>= 5;
    const int ot = bt & 3;        const int b = bt >> 2;
    const int gr0 = row_tile * TR, gc0 = col_tile * TC, o_base = ot * OT;
    const int og = tid >> 4, pg = tid & 15;
    const int prow = pg >> 2, pcol4 = (pg & 3) * 4;
    const int orow = gr0 + prow, ocol0 = gc0 + pcol4;
    float mask_r[9][4];
#pragma unroll
    for (int k = 0; k < 9; ++k)
#pragma unroll
        for (int j = 0; j < 4; ++j)
            mask_r[k][j] = mask[k * NPIX + orow * W_ + (ocol0 + j)];
    float acc[4][4];
#pragma unroll
    for (int a = 0; a < 4; ++a)
#pragma unroll
        for (int j = 0; j < 4; ++j) acc[a][j] = 0.f;
    for (int chunk = 0; chunk < C_ / CKC; ++chunk) {
        const int c0 = chunk * CKC;
#pragma unroll
        for (int i = 0; i < 36; ++i) {
            const int flat = i * 256 + tid;
            const int o_l = flat / 144;
            const int r = flat - o_l * 144;
            const int c_l = r / 9;
            const int kk = r - c_l * 9;
            w_s[c_l][kk][o_l] = wg[(o_base + o_l) * (C_ * 9) + (c0 + c_l) * 9 + kk];
        }
#pragma unroll
        for (int i = 0; i < 7; ++i) {
            const int flat = i * 256 + tid;
            if (flat < CKC * 108) {
                const int c_l = flat / 108;
                const int r = flat - c_l * 108;
                const int row = r / 18, colx = r - row * 18;
                const int grow = gr0 - 1 + row, gcol = gc0 - 1 + colx;
                float v = 0.f;
                if ((unsigned)grow < (unsigned)H_ && (unsigned)gcol < (unsigned)W_)
                    v = xin[((b * C_ + c0 + c_l) * H_ + grow) * W_ + gcol];
                x_s[c_l][row][colx] = v;
            }
        }
        __syncthreads();
#pragma unroll
        for (int dyy = 0; dyy < 3; ++dyy) {
            float acck[3][4][4];
#pragma unroll
            for (int dxx = 0; dxx < 3; ++dxx)
#pragma unroll
                for (int a = 0; a < 4; ++a)
#pragma unroll
                    for (int j = 0; j < 4; ++j) acck[dxx][a][j] = 0.f;
#pragma unroll 4
            for (int c = 0; c < CKC; ++c) {
                const float4 xv4 = *(const float4*)&x_s[c][prow + dyy][pcol4];
                const float2 xv2 = *(const float2*)&x_s[c][prow + dyy][pcol4 + 4];
                const float xv[6] = {xv4.x, xv4.y, xv4.z, xv4.w, xv2.x, xv2.y};
#pragma unroll
                for (int dxx = 0; dxx < 3; ++dxx) {
                    const float4 wv = *(const float4*)&w_s[c][dyy * 3 + dxx][og * 4];
                    const float wa[4] = {wv.x, wv.y, wv.z, wv.w};
#pragma unroll
                    for (int a = 0; a < 4; ++a)
#pragma unroll
                        for (int j = 0; j < 4; ++j)
                            acck[dxx][a][j] = fmaf(wa[a], xv[j + dxx], acck[dxx][a][j]);
                }
            }
#pragma unroll
            for (int dxx = 0; dxx < 3; ++dxx) {
                const int k = dyy * 3 + dxx;
#pragma unroll
                for (int a = 0; a < 4; ++a)
#pragma unroll
                    for (int j = 0; j < 4; ++j)
                        acc[a][j] = fmaf(mask_r[k][j], acck[dxx][a][j], acc[a][j]);
            }
        }
        __syncthreads();
    }
#pragma unroll
    for (int a = 0; a < 4; ++a) {
        const int o = o_base + og * 4 + a;
#pragma unroll
        for (int j = 0; j < 4; ++j) {
            const int idx = ((b * C_ + o) * H_ + orow) * W_ + (ocol0 + j);
            const float d = acc[a][j];
            xout[idx] = xin[idx] + d / (1.0f + fabsf(d));
        }
    }
}

extern "C" void kernel_launch(void* const* d_in, const int* in_sizes, int n_in,
                              void* d_out, int out_size, void* d_ws, size_t ws_size,
                              hipStream_t stream) {
    const float* retina = (const float*)d_in[0];
    const float* wg     = (const float*)d_in[1];
    const float* mask   = (const float*)d_in[2];
    float* out = (float*)d_out;

    const size_t need = 0x4200000;   // wb5+zb (2M) + hiA/loA (2x32M)

    if (ws_size >= need) {
        unsigned short* wb5 = (unsigned short*)d_ws;
        unsigned short* zb  = (unsigned short*)((char*)d_ws + 0x120000);
        unsigned short* hiA = (unsigned short*)((char*)d_ws + 0x200000);
        unsigned short* loA = (unsigned short*)((char*)d_ws + 0x2200000);
        unsigned short* hiB = (unsigned short*)d_out;              // first 32 MB of out
        unsigned short* loB = hiB + (size_t)B_ * NPIX * C_;        // second 32 MB

        hipFuncSetAttribute((const void*)nca_v11,
                            hipFuncAttributeMaxDynamicSharedMemorySize, LDS_TOTAL);

        prep_w5<<<2305, 256, 0, stream>>>(wg, wb5, zb);
        prep_split<<<4096, 256, 0, stream>>>(retina, hiB, loB);    // state starts in B (d_out)

        // B->A->B->A->B->A : final state lands in ws, then transpose into d_out
        nca_v11<<<256, 512, LDS_TOTAL, stream>>>(hiB, loB, wb5, zb, mask, hiA, loA);
        nca_v11<<<256, 512, LDS_TOTAL, stream>>>(hiA, loA, wb5, zb, mask, hiB, loB);
        nca_v11<<<256, 512, LDS_TOTAL, stream>>>(hiB, loB, wb5, zb, mask, hiA, loA);
        nca_v11<<<256, 512, LDS_TOTAL, stream>>>(hiA, loA, wb5, zb, mask, hiB, loB);
        nca_v11<<<256, 512, LDS_TOTAL, stream>>>(hiB, loB, wb5, zb, mask, hiA, loA);
        shadows_to_f32<<<2048, 256, 0, stream>>>(hiA, loA, out);
    } else {
        float* ws = (float*)d_ws;
        const int nblocks = B_ * (C_ / OT) * (H_ / TR) * (W_ / TC);
        const float* src = retina;
        float* dsts[5] = {out, ws, out, ws, out};
        for (int s = 0; s < 5; ++s) {
            nca_step_f32<<<dim3(nblocks), dim3(256), 0, stream>>>(src, wg, mask, dsts[s]);
            src = dsts[s];
        }
    }
}

// Round 11
// 500.621 us; speedup vs baseline: 1.8922x; 1.0196x over previous
//
#include <hip/hip_runtime.h>
#include <math.h>
#include <stdint.h>

#define B_ 4
#define C_ 256
#define H_ 128
#define W_ 128
#define NPIX (H_*W_)

typedef short bf16x8 __attribute__((ext_vector_type(8)));
typedef int   i32x4  __attribute__((ext_vector_type(4)));
typedef float f32x4  __attribute__((ext_vector_type(4)));
typedef float f32x16 __attribute__((ext_vector_type(16)));
typedef unsigned short u16x4 __attribute__((ext_vector_type(4)));

// ---- LDS map (v7's, verified): x dbuf + W dbuf; epilogue reuses [0,128K) ----
#define XSZ   41984              // 328 slots * 128 B (18x18 halo, 64-c quarter)
#define WOFF  (2*XSZ)            // 83968
#define WSL   32768              // one W slice: 256 o * 64 c * 2 B
#define SCR   (WOFF + 2*WSL)     // 149504: 1 KB scratch for dummy stage ops
#define LDS_TOTAL (SCR + 1024)   // 150528

__device__ __forceinline__ unsigned short f2bf_rne(float v) {
    uint32_t b = __float_as_uint(v);
    return (unsigned short)((b + 0x7fff + ((b >> 16) & 1)) >> 16);
}
__device__ __forceinline__ float bf2f(unsigned short h) {
    return __uint_as_float(((uint32_t)h) << 16);
}

// ---- prep: 36 W slices (v7's layout): sl = qt*9 + k; image[o][u'][e],
//      u' = u ^ (o&7), c = qt*64 + u*8 + e
__global__ __launch_bounds__(256)
void prep_w(const float* __restrict__ wg, unsigned short* __restrict__ wb,
            unsigned short* __restrict__ zb) {
    if (blockIdx.x == 2304) { if (threadIdx.x < 128) zb[threadIdx.x] = 0; return; }
    int f = blockIdx.x * 256 + threadIdx.x;          // < 589824
    int sl = f >> 14, within = f & 16383;
    int o = within >> 6, t = within & 63;
    int up = t >> 3, e = t & 7;
    int qt = sl / 9, k = sl - qt * 9;
    int c = qt * 64 + ((up ^ (o & 7)) << 3) + e;
    wb[f] = f2bf_rne(wg[(o * C_ + c) * 9 + k]);
}

// ---- prep: retina fp32 (B,C,H,W) -> channel-last hi/lo bf16 shadows (B,H,W,C)
__global__ __launch_bounds__(256)
void prep_split(const float* __restrict__ retina, unsigned short* __restrict__ hi,
                unsigned short* __restrict__ lo) {
    __shared__ unsigned int t[64][65];
    int bid = blockIdx.x;
    const int wt = bid & 1;        bid >>= 1;
    const int h  = bid & 127;      bid >>= 7;
    const int ct = bid & 3;        const int b = bid >> 2;
    const int tid = threadIdx.x;
    const int ci4 = tid >> 6, wi = tid & 63;
    #pragma unroll
    for (int cc = 0; cc < 16; ++cc) {
        int c_loc = cc * 4 + ci4;
        float v = retina[((size_t)(b * C_ + ct * 64 + c_loc) * H_ + h) * W_ + wt * 64 + wi];
        unsigned short hv = f2bf_rne(v);
        unsigned short lv = f2bf_rne(v - bf2f(hv));
        t[c_loc][wi] = (unsigned)hv | ((unsigned)lv << 16);
    }
    __syncthreads();
    const int p = tid >> 2, j = tid & 3;
    size_t base = (((size_t)(b * H_ + h) * W_ + wt * 64 + p) << 8) + ct * 64 + j * 16;
    u16x4 hv4[4], lv4[4];
    #pragma unroll
    for (int e = 0; e < 16; ++e) {
        unsigned u = t[j * 16 + e][p];
        hv4[e >> 2][e & 3] = (unsigned short)(u & 0xffffu);
        lv4[e >> 2][e & 3] = (unsigned short)(u >> 16);
    }
    #pragma unroll
    for (int q2 = 0; q2 < 4; ++q2) {
        *(u16x4*)(hi + base + q2 * 4) = hv4[q2];
        *(u16x4*)(lo + base + q2 * 4) = lv4[q2];
    }
}

// ---- staging at 16 waves: W slice = 2 ops/wave, x quarter = 3 ops/wave ----
__device__ __forceinline__ void stage_w(const unsigned short* __restrict__ wb,
                                        char* smem, int woff, int sl, int wid, int l) {
    const char* src = (const char*)wb + ((size_t)sl << 15);
    #pragma unroll
    for (int op = 0; op < 2; ++op) {
        const int seg = ((op << 4) + wid) << 10;     // 32 segments of 1 KB
        __builtin_amdgcn_global_load_lds(
            (const __attribute__((address_space(1))) uint32_t*)(src + seg + l * 16),
            (__attribute__((address_space(3))) uint32_t*)(smem + woff + seg), 16, 0, 0);
    }
    __builtin_amdgcn_sched_barrier(0);
}

__device__ __forceinline__ void stage_x(const unsigned short* __restrict__ hi_in,
                                        const unsigned short* __restrict__ zb,
                                        char* smem, int b, int tr, int tc,
                                        int qt, int wid, int l) {
    const int slot_r = l >> 3, sub = l & 7;
    const int xoff = (qt & 1) ? XSZ : 0;
    #pragma unroll
    for (int op = 0; op < 3; ++op) {
        const int sbase = ((op << 4) + wid) << 3;    // 0..376 step 8, unique
        const int s = sbase + slot_r;
        const int rr = (s * 3641) >> 16;             // s/18 for s<=383
        const int hc = s - rr * 18;
        const int h = tr * 16 + rr - 1;
        const int w = tc * 16 + hc - 1;
        const unsigned short* src;
        int dst;
        if (sbase < 328) {
            dst = xoff + (sbase << 7);
            if (s < 324 && (unsigned)h < 128u && (unsigned)w < 128u)
                src = hi_in + (((size_t)((b * 128 + h) * 128 + w)) << 8) + (qt << 6)
                            + ((sub ^ (s & 7)) << 3);   // swizzle folded into src
            else
                src = zb + (sub << 3);
        } else {
            dst = SCR;
            src = zb + (sub << 3);
        }
        __builtin_amdgcn_global_load_lds(
            (const __attribute__((address_space(1))) uint32_t*)src,
            (__attribute__((address_space(3))) uint32_t*)(smem + dst), 16, 0, 0);
    }
    __builtin_amdgcn_sched_barrier(0);
}

// ---- main step: 256 blocks, 1024 thr (16 waves = og4 x ph4), 32x32x16 MFMA,
//      mo2 x n2 frags/wave (acc 64), counted-vmcnt pipeline, 4 waves/SIMD
__global__ __launch_bounds__(1024, 4)
void nca_v12(const unsigned short* __restrict__ hi_in,
             const unsigned short* __restrict__ lo_in,
             const unsigned short* __restrict__ wb,
             const unsigned short* __restrict__ zb,
             const float* __restrict__ mask,
             unsigned short* __restrict__ hi_out,
             unsigned short* __restrict__ lo_out)
{
    extern __shared__ char smem[];
    const int tid = threadIdx.x;
    const int l = tid & 63, wid = tid >> 6;          // 16 waves
    const int og = wid & 3, ph = wid >> 2;           // 64-o group x 4-row group
    const int lane31 = l & 31, khalf = l >> 5;
    const int col = l & 15, rowin = (l >> 4) & 1;

    int bid = blockIdx.x;
    const int tc = bid & 7; bid >>= 3;
    const int tr = bid & 7; const int b = bid >> 3;

    // mask bits (9 taps x 2 row-pairs), consumed before staging
    unsigned mbits = 0;
    #pragma unroll
    for (int k = 0; k < 9; ++k) {
        #pragma unroll
        for (int n = 0; n < 2; ++n) {
            const int h = tr * 16 + ph * 4 + n * 2 + rowin;
            const int w = tc * 16 + col;
            unsigned bit = (mask[k * NPIX + h * W_ + w] != 0.f) ? 1u : 0u;
            mbits |= bit << (k * 2 + n);
        }
    }
    __builtin_amdgcn_sched_barrier(0);

    // prologue (per wave): W0(2) W1(2) X0(3) X1(3)
    stage_w(wb, smem, WOFF,       0, wid, l);
    stage_w(wb, smem, WOFF + WSL, 1, wid, l);
    stage_x(hi_in, zb, smem, b, tr, tc, 0, wid, l);
    stage_x(hi_in, zb, smem, b, tr, tc, 1, wid, l);

    int sB[2];
    #pragma unroll
    for (int n = 0; n < 2; ++n) sB[n] = (ph * 4 + n * 2 + rowin) * 18 + col;
    int abase[2], aswz[2];
    #pragma unroll
    for (int mo = 0; mo < 2; ++mo) {
        int o_l = og * 64 + mo * 32 + lane31;
        abase[mo] = o_l << 7;
        aswz[mo] = o_l & 7;
    }

    f32x16 zv;
    #pragma unroll
    for (int r = 0; r < 16; ++r) zv[r] = 0.f;
    f32x16 acc[2][2];
    #pragma unroll
    for (int mo = 0; mo < 2; ++mo)
        #pragma unroll
        for (int n = 0; n < 2; ++n) acc[mo][n] = zv;

    #pragma unroll 1
    for (int qt = 0; qt < 4; ++qt) {
        const char* xbuf = smem + ((qt & 1) ? XSZ : 0);
        #pragma unroll 1
        for (int k = 0; k < 9; ++k) {
            const int sl = qt * 9 + k;
            // counted waits (W=2 ops, X=3 ops/wave), derived from issue order:
            if (sl == 0)                          asm volatile("s_waitcnt vmcnt(3)" ::: "memory");
            else if (sl == 1)                     asm volatile("s_waitcnt vmcnt(5)" ::: "memory");
            else if (k <= 1 && qt >= 1 && qt <= 2) asm volatile("s_waitcnt vmcnt(5)" ::: "memory");
            else if (sl == 35)                    asm volatile("s_waitcnt vmcnt(0)" ::: "memory");
            else                                  asm volatile("s_waitcnt vmcnt(2)" ::: "memory");
            __builtin_amdgcn_sched_barrier(0);
            __builtin_amdgcn_s_barrier();

            const int dy = (k * 11) >> 5;
            const int dx = k - dy * 3;
            const int doff = dy * 18 + dx;
            const char* wbuf = smem + WOFF + ((sl & 1) ? WSL : 0);
            const unsigned mk = mbits >> (k * 2);

            int sx[2];
            #pragma unroll
            for (int n = 0; n < 2; ++n) sx[n] = sB[n] + doff;

            __builtin_amdgcn_s_setprio(1);
            #pragma unroll
            for (int ks = 0; ks < 4; ++ks) {
                const int ua = ks * 2 + khalf;               // 0..7
                bf16x8 av[2];
                #pragma unroll
                for (int mo = 0; mo < 2; ++mo)
                    av[mo] = *(const bf16x8*)(wbuf + abase[mo] + ((ua ^ aswz[mo]) << 4));
                bf16x8 bv[2];
                #pragma unroll
                for (int n = 0; n < 2; ++n) {
                    i32x4 braw = *(const i32x4*)(xbuf + (sx[n] << 7) + ((ua ^ (sx[n] & 7)) << 4));
                    const int mm = -(int)((mk >> n) & 1u);
                    #pragma unroll
                    for (int w4 = 0; w4 < 4; ++w4) braw[w4] &= mm;   // binary mask, exact
                    bv[n] = __builtin_bit_cast(bf16x8, braw);
                }
                #pragma unroll
                for (int mo = 0; mo < 2; ++mo)
                    #pragma unroll
                    for (int n = 0; n < 2; ++n)
                        acc[mo][n] = __builtin_amdgcn_mfma_f32_32x32x16_bf16(av[mo], bv[n], acc[mo][n], 0, 0, 0);
            }
            __builtin_amdgcn_s_setprio(0);

            asm volatile("" ::: "memory");
            __builtin_amdgcn_s_barrier();
            if (sl + 2 < 36)
                stage_w(wb, smem, WOFF + ((sl & 1) ? WSL : 0), sl + 2, wid, l);
            if (k == 8 && qt < 2)
                stage_x(hi_in, zb, smem, b, tr, tc, qt + 2, wid, l);
        }
    }

    // ---- epilogue: 2 phases x 128 px; LDS transpose -> coalesced hi/lo RMW
    __syncthreads();
    #pragma unroll 1
    for (int f = 0; f < 2; ++f) {
        if ((ph >> 1) == f) {
            #pragma unroll
            for (int n = 0; n < 2; ++n) {
                const int lrow = (ph & 1) * 4 + n * 2 + rowin;            // 0..7
                const int pl = lrow * 16 + col;                            // 0..127
                #pragma unroll
                for (int mo = 0; mo < 2; ++mo)
                    #pragma unroll
                    for (int rq = 0; rq < 4; ++rq) {
                        const int u = og * 16 + mo * 8 + rq * 2 + khalf;   // 0..63
                        f32x4 v;
                        v[0] = acc[mo][n][rq * 4 + 0];
                        v[1] = acc[mo][n][rq * 4 + 1];
                        v[2] = acc[mo][n][rq * 4 + 2];
                        v[3] = acc[mo][n][rq * 4 + 3];
                        *(f32x4*)(smem + pl * 1024 + ((u ^ (pl & 7)) << 4)) = v;
                    }
            }
        }
        __syncthreads();
        #pragma unroll
        for (int it = 0; it < 8; ++it) {
            const int pl = it * 16 + wid;                // unique per (it,wid)
            const int h = tr * 16 + f * 8 + (pl >> 4);
            const int w = tc * 16 + (pl & 15);
            const f32x4 d4 = *(const f32x4*)(smem + pl * 1024 + ((l ^ (pl & 7)) << 4));
            const size_t base = (((size_t)((b * 128 + h) * 128 + w)) << 8) + l * 4;
            const u16x4 h4 = *(const u16x4*)(hi_in + base);
            const u16x4 l4 = *(const u16x4*)(lo_in + base);
            u16x4 ho, lo2;
            #pragma unroll
            for (int r = 0; r < 4; ++r) {
                const float xv = bf2f(h4[r]) + bf2f(l4[r]);
                const float d = d4[r];
                const float xn = xv + d / (1.f + fabsf(d));
                ho[r] = f2bf_rne(xn);
                lo2[r] = f2bf_rne(xn - bf2f(ho[r]));
            }
            *(u16x4*)(hi_out + base) = ho;
            *(u16x4*)(lo_out + base) = lo2;
        }
        if (f == 0) __syncthreads();
    }
}

// ---- final: channel-last hi/lo shadows -> fp32 (B,C,H,W) via LDS transpose
__global__ __launch_bounds__(256)
void shadows_to_f32(const unsigned short* __restrict__ hi,
                    const unsigned short* __restrict__ lo,
                    float* __restrict__ out)
{
    __shared__ float t[64][132];
    int bid = blockIdx.x;
    const int ct = bid & 3;  bid >>= 2;
    const int h  = bid & 127; const int b = bid >> 7;
    const int tid = threadIdx.x;
    #pragma unroll
    for (int pass = 0; pass < 8; ++pass) {
        const int w = pass * 16 + (tid >> 4);
        const int c0 = (tid & 15) * 4;
        const size_t base = (((size_t)((b * 128 + h) * 128 + w)) << 8) + ct * 64 + c0;
        const u16x4 hv = *(const u16x4*)(hi + base);
        const u16x4 lv = *(const u16x4*)(lo + base);
        #pragma unroll
        for (int e = 0; e < 4; ++e) t[c0 + e][w] = bf2f(hv[e]) + bf2f(lv[e]);
    }
    __syncthreads();
    #pragma unroll
    for (int pass = 0; pass < 8; ++pass) {
        const int c = pass * 8 + (tid >> 5);
        const int w = (tid & 31) * 4;
        float4 v = make_float4(t[c][w], t[c][w + 1], t[c][w + 2], t[c][w + 3]);
        *(float4*)(out + ((size_t)(b * C_ + ct * 64 + c) * H_ + h) * W_ + w) = v;
    }
}

// ================= fp32 fallback (only if ws too small) =================
#define OT 64
#define TR 4
#define TC 16
#define CKC 16
__global__ __launch_bounds__(256)
void nca_step_f32(const float* __restrict__ xin, const float* __restrict__ wg,
                  const float* __restrict__ mask, float* __restrict__ xout)
{
    __shared__ __align__(16) float w_s[CKC][9][OT];
    __shared__ __align__(16) float x_s[CKC][TR + 2][20];
    const int tid = threadIdx.x;
    int bt = blockIdx.x;
    const int col_tile = bt & 7;  bt >>= 3;
    const int row_tile = bt & 31; bt >>= 5;
    const int ot = bt & 3;        const int b = bt >> 2;
    const int gr0 = row_tile * TR, gc0 = col_tile * TC, o_base = ot * OT;
    const int og = tid >> 4, pg = tid & 15;
    const int prow = pg >> 2, pcol4 = (pg & 3) * 4;
    const int orow = gr0 + prow, ocol0 = gc0 + pcol4;
    float mask_r[9][4];
#pragma unroll
    for (int k = 0; k < 9; ++k)
#pragma unroll
        for (int j = 0; j < 4; ++j)
            mask_r[k][j] = mask[k * NPIX + orow * W_ + (ocol0 + j)];
    float acc[4][4];
#pragma unroll
    for (int a = 0; a < 4; ++a)
#pragma unroll
        for (int j = 0; j < 4; ++j) acc[a][j] = 0.f;
    for (int chunk = 0; chunk < C_ / CKC; ++chunk) {
        const int c0 = chunk * CKC;
#pragma unroll
        for (int i = 0; i < 36; ++i) {
            const int flat = i * 256 + tid;
            const int o_l = flat / 144;
            const int r = flat - o_l * 144;
            const int c_l = r / 9;
            const int kk = r - c_l * 9;
            w_s[c_l][kk][o_l] = wg[(o_base + o_l) * (C_ * 9) + (c0 + c_l) * 9 + kk];
        }
#pragma unroll
        for (int i = 0; i < 7; ++i) {
            const int flat = i * 256 + tid;
            if (flat < CKC * 108) {
                const int c_l = flat / 108;
                const int r = flat - c_l * 108;
                const int row = r / 18, colx = r - row * 18;
                const int grow = gr0 - 1 + row, gcol = gc0 - 1 + colx;
                float v = 0.f;
                if ((unsigned)grow < (unsigned)H_ && (unsigned)gcol < (unsigned)W_)
                    v = xin[((b * C_ + c0 + c_l) * H_ + grow) * W_ + gcol];
                x_s[c_l][row][colx] = v;
            }
        }
        __syncthreads();
#pragma unroll
        for (int dyy = 0; dyy < 3; ++dyy) {
            float acck[3][4][4];
#pragma unroll
            for (int dxx = 0; dxx < 3; ++dxx)
#pragma unroll
                for (int a = 0; a < 4; ++a)
#pragma unroll
                    for (int j = 0; j < 4; ++j) acck[dxx][a][j] = 0.f;
#pragma unroll 4
            for (int c = 0; c < CKC; ++c) {
                const float4 xv4 = *(const float4*)&x_s[c][prow + dyy][pcol4];
                const float2 xv2 = *(const float2*)&x_s[c][prow + dyy][pcol4 + 4];
                const float xv[6] = {xv4.x, xv4.y, xv4.z, xv4.w, xv2.x, xv2.y};
#pragma unroll
                for (int dxx = 0; dxx < 3; ++dxx) {
                    const float4 wv = *(const float4*)&w_s[c][dyy * 3 + dxx][og * 4];
                    const float wa[4] = {wv.x, wv.y, wv.z, wv.w};
#pragma unroll
                    for (int a = 0; a < 4; ++a)
#pragma unroll
                        for (int j = 0; j < 4; ++j)
                            acck[dxx][a][j] = fmaf(wa[a], xv[j + dxx], acck[dxx][a][j]);
                }
            }
#pragma unroll
            for (int dxx = 0; dxx < 3; ++dxx) {
                const int k = dyy * 3 + dxx;
#pragma unroll
                for (int a = 0; a < 4; ++a)
#pragma unroll
                    for (int j = 0; j < 4; ++j)
                        acc[a][j] = fmaf(mask_r[k][j], acck[dxx][a][j], acc[a][j]);
            }
        }
        __syncthreads();
    }
#pragma unroll
    for (int a = 0; a < 4; ++a) {
        const int o = o_base + og * 4 + a;
#pragma unroll
        for (int j = 0; j < 4; ++j) {
            const int idx = ((b * C_ + o) * H_ + orow) * W_ + (ocol0 + j);
            const float d = acc[a][j];
            xout[idx] = xin[idx] + d / (1.0f + fabsf(d));
        }
    }
}

extern "C" void kernel_launch(void* const* d_in, const int* in_sizes, int n_in,
                              void* d_out, int out_size, void* d_ws, size_t ws_size,
                              hipStream_t stream) {
    const float* retina = (const float*)d_in[0];
    const float* wg     = (const float*)d_in[1];
    const float* mask   = (const float*)d_in[2];
    float* out = (float*)d_out;

    const size_t need = 0x4200000;   // wb+zb (2M) + hiA/loA (2x32M)

    if (ws_size >= need) {
        unsigned short* wb  = (unsigned short*)d_ws;
        unsigned short* zb  = (unsigned short*)((char*)d_ws + 0x120000);
        unsigned short* hiA = (unsigned short*)((char*)d_ws + 0x200000);
        unsigned short* loA = (unsigned short*)((char*)d_ws + 0x2200000);
        unsigned short* hiB = (unsigned short*)d_out;              // first 32 MB of out
        unsigned short* loB = hiB + (size_t)B_ * NPIX * C_;        // second 32 MB

        hipFuncSetAttribute((const void*)nca_v12,
                            hipFuncAttributeMaxDynamicSharedMemorySize, LDS_TOTAL);

        prep_w<<<2305, 256, 0, stream>>>(wg, wb, zb);
        prep_split<<<4096, 256, 0, stream>>>(retina, hiB, loB);    // state starts in B (d_out)

        // B->A->B->A->B->A : final state lands in ws, then transpose into d_out
        nca_v12<<<256, 1024, LDS_TOTAL, stream>>>(hiB, loB, wb, zb, mask, hiA, loA);
        nca_v12<<<256, 1024, LDS_TOTAL, stream>>>(hiA, loA, wb, zb, mask, hiB, loB);
        nca_v12<<<256, 1024, LDS_TOTAL, stream>>>(hiB, loB, wb, zb, mask, hiA, loA);
        nca_v12<<<256, 1024, LDS_TOTAL, stream>>>(hiA, loA, wb, zb, mask, hiB, loB);
        nca_v12<<<256, 1024, LDS_TOTAL, stream>>>(hiB, loB, wb, zb, mask, hiA, loA);
        shadows_to_f32<<<2048, 256, 0, stream>>>(hiA, loA, out);
    } else {
        float* ws = (float*)d_ws;
        const int nblocks = B_ * (C_ / OT) * (H_ / TR) * (W_ / TC);
        const float* src = retina;
        float* dsts[5] = {out, ws, out, ws, out};
        for (int s = 0; s < 5; ++s) {
            nca_step_f32<<<dim3(nblocks), dim3(256), 0, stream>>>(src, wg, mask, dsts[s]);
            src = dsts[s];
        }
    }
}

// Round 12
// 480.810 us; speedup vs baseline: 1.9702x; 1.0412x over previous
//
#include <hip/hip_runtime.h>
#include <math.h>
#include <stdint.h>

#define B_ 4
#define C_ 256
#define H_ 128
#define W_ 128
#define NPIX (H_*W_)

typedef short bf16x8 __attribute__((ext_vector_type(8)));
typedef int   i32x4  __attribute__((ext_vector_type(4)));
typedef float f32x4  __attribute__((ext_vector_type(4)));
typedef float f32x16 __attribute__((ext_vector_type(16)));
typedef unsigned short u16x4 __attribute__((ext_vector_type(4)));

// ---- LDS map (v7, verified best) ----
#define XSZ   41984              // 328 slots * 128 B (18x18 halo, 64-c quarter)
#define WOFF  (2*XSZ)            // 83968
#define WSL   32768              // one W slice: 256 o * 64 c * 2 B
#define SCR   (WOFF + 2*WSL)     // 149504: 1 KB scratch for dummy stage ops
#define LDS_TOTAL (SCR + 1024)   // 150528

__device__ __forceinline__ unsigned short f2bf_rne(float v) {
    uint32_t b = __float_as_uint(v);
    return (unsigned short)((b + 0x7fff + ((b >> 16) & 1)) >> 16);
}
__device__ __forceinline__ float bf2f(unsigned short h) {
    return __uint_as_float(((uint32_t)h) << 16);
}

// ---- prep: 36 W slices, slice sl = qt*9 + k; image[o][u'][e] with u' = u ^ (o&7),
//      c = qt*64 + u*8 + e.  Block 2304 zeroes the zero block.
__global__ __launch_bounds__(256)
void prep_w(const float* __restrict__ wg, unsigned short* __restrict__ wb,
            unsigned short* __restrict__ zb) {
    if (blockIdx.x == 2304) { if (threadIdx.x < 128) zb[threadIdx.x] = 0; return; }
    int f = blockIdx.x * 256 + threadIdx.x;          // < 589824
    int sl = f >> 14, within = f & 16383;
    int o = within >> 6, t = within & 63;
    int up = t >> 3, e = t & 7;
    int qt = sl / 9, k = sl - qt * 9;
    int c = qt * 64 + ((up ^ (o & 7)) << 3) + e;
    wb[f] = f2bf_rne(wg[(o * C_ + c) * 9 + k]);
}

// ---- prep: retina fp32 (B,C,H,W) -> channel-last hi/lo bf16 shadows (B,H,W,C)
__global__ __launch_bounds__(256)
void prep_split(const float* __restrict__ retina, unsigned short* __restrict__ hi,
                unsigned short* __restrict__ lo) {
    __shared__ unsigned int t[64][65];
    int bid = blockIdx.x;
    const int wt = bid & 1;        bid >>= 1;
    const int h  = bid & 127;      bid >>= 7;
    const int ct = bid & 3;        const int b = bid >> 2;
    const int tid = threadIdx.x;
    const int ci4 = tid >> 6, wi = tid & 63;
    #pragma unroll
    for (int cc = 0; cc < 16; ++cc) {
        int c_loc = cc * 4 + ci4;
        float v = retina[((size_t)(b * C_ + ct * 64 + c_loc) * H_ + h) * W_ + wt * 64 + wi];
        unsigned short hv = f2bf_rne(v);
        unsigned short lv = f2bf_rne(v - bf2f(hv));
        t[c_loc][wi] = (unsigned)hv | ((unsigned)lv << 16);
    }
    __syncthreads();
    const int p = tid >> 2, j = tid & 3;
    size_t base = (((size_t)(b * H_ + h) * W_ + wt * 64 + p) << 8) + ct * 64 + j * 16;
    u16x4 hv4[4], lv4[4];
    #pragma unroll
    for (int e = 0; e < 16; ++e) {
        unsigned u = t[j * 16 + e][p];
        hv4[e >> 2][e & 3] = (unsigned short)(u & 0xffffu);
        lv4[e >> 2][e & 3] = (unsigned short)(u >> 16);
    }
    #pragma unroll
    for (int q2 = 0; q2 < 4; ++q2) {
        *(u16x4*)(hi + base + q2 * 4) = hv4[q2];
        *(u16x4*)(lo + base + q2 * 4) = lv4[q2];
    }
}

// ---- staging: per-wave uniform op counts (W slice = 4 glds/wave, x quarter = 6)
__device__ __forceinline__ void stage_w(const unsigned short* __restrict__ wb_all,
                                        char* smem, int woff, int sl, int wid, int l) {
    const char* src = (const char*)wb_all + ((size_t)sl << 15);
    #pragma unroll
    for (int j = 0; j < 4; ++j) {
        const int seg = ((j << 3) + wid) << 10;      // (j*8 + wid) * 1024
        __builtin_amdgcn_global_load_lds(
            (const __attribute__((address_space(1))) uint32_t*)(src + seg + l * 16),
            (__attribute__((address_space(3))) uint32_t*)(smem + woff + seg), 16, 0, 0);
    }
    __builtin_amdgcn_sched_barrier(0);
}

__device__ __forceinline__ void stage_x(const unsigned short* __restrict__ hi_in,
                                        const unsigned short* __restrict__ zb,
                                        char* smem, int xoff, int b, int tr, int tc,
                                        int qt, int wid, int l) {
    const int slot_r = l >> 3, sub = l & 7;
    #pragma unroll
    for (int op = 0; op < 6; ++op) {
        const int sbase = (op << 6) + (wid << 3);    // 0..383, wave-uniform
        const int s = sbase + slot_r;
        const int rr = (s * 3641) >> 16;             // s/18 for s<=383
        const int hc = s - rr * 18;
        const int h = tr * 16 + rr - 1;
        const int w = tc * 16 + hc - 1;
        const unsigned short* src;
        int dst;
        if (sbase < 328) {                           // valid op (uniform)
            dst = xoff + (sbase << 7);
            if ((unsigned)h < 128u && (unsigned)w < 128u)
                src = hi_in + ((((size_t)(b * 128 + h) << 7) + w) << 8) + (qt << 6)
                            + ((sub ^ (s & 7)) << 3);  // swizzle folded into global addr
            else
                src = zb + (sub << 3);               // zero halo
        } else {                                     // dummy op: keep vmcnt uniform
            dst = SCR;
            src = zb + (sub << 3);
        }
        __builtin_amdgcn_global_load_lds(
            (const __attribute__((address_space(1))) uint32_t*)src,
            (__attribute__((address_space(3))) uint32_t*)(smem + dst), 16, 0, 0);
    }
    __builtin_amdgcn_sched_barrier(0);
}

// ---- main step: 8 waves, 32x32x16 MFMA, 4x2 frags/wave, counted-vmcnt pipeline,
//      LDS-transpose epilogue; final_step writes fp32 NCHW directly
__global__ __launch_bounds__(512, 2)
void nca_v13(const unsigned short* __restrict__ hi_in,
             const unsigned short* __restrict__ lo_in,
             const unsigned short* __restrict__ wb,
             const unsigned short* __restrict__ zb,
             const float* __restrict__ mask,
             unsigned short* __restrict__ hi_out,
             unsigned short* __restrict__ lo_out,
             float* __restrict__ out_f32,
             int final_step)
{
    extern __shared__ char smem[];
    const int tid = threadIdx.x;
    const int l = tid & 63, wid = tid >> 6;          // 8 waves
    const int wave_o = wid & 1, wave_p = wid >> 1;   // o-halves x 4 row-groups
    const int lane31 = l & 31, khalf = l >> 5;
    const int col = l & 15, rowin = (l >> 4) & 1;

    int bid = blockIdx.x;
    const int tc = bid & 7; bid >>= 3;
    const int tr = bid & 7; const int b = bid >> 3;

    // mask bits first (consumed immediately so vmcnt counting below stays exact)
    unsigned mbits = 0;
    #pragma unroll
    for (int k = 0; k < 9; ++k) {
        #pragma unroll
        for (int n = 0; n < 2; ++n) {
            const int h = tr * 16 + wave_p * 4 + n * 2 + rowin;
            const int w = tc * 16 + col;
            unsigned bit = (mask[k * NPIX + h * W_ + w] != 0.f) ? 1u : 0u;
            mbits |= bit << (k * 2 + n);
        }
    }
    __builtin_amdgcn_sched_barrier(0);

    // prologue queue (per wave): W0(4) W1(4) X0(6) X1(6)
    stage_w(wb, smem, WOFF,       0, wid, l);
    stage_w(wb, smem, WOFF + WSL, 1, wid, l);
    stage_x(hi_in, zb, smem, 0,   b, tr, tc, 0, wid, l);
    stage_x(hi_in, zb, smem, XSZ, b, tr, tc, 1, wid, l);

    int sB[2];
    #pragma unroll
    for (int n = 0; n < 2; ++n) sB[n] = (wave_p * 4 + n * 2 + rowin) * 18 + col;
    int abase[4], aswz[4];
    #pragma unroll
    for (int mo = 0; mo < 4; ++mo) {
        int o_l = wave_o * 128 + mo * 32 + lane31;
        abase[mo] = o_l << 7;
        aswz[mo] = o_l & 7;
    }

    f32x16 zv;
    #pragma unroll
    for (int r = 0; r < 16; ++r) zv[r] = 0.f;
    f32x16 acc[4][2];
    #pragma unroll
    for (int mo = 0; mo < 4; ++mo)
        #pragma unroll
        for (int n = 0; n < 2; ++n) acc[mo][n] = zv;

    #pragma unroll 1
    for (int qt = 0; qt < 4; ++qt) {
        const char* xbuf = smem + ((qt & 1) ? XSZ : 0);
        #pragma unroll 1
        for (int k = 0; k < 9; ++k) {
            const int sl = qt * 9 + k;
            // per-wave counted waits (W=4 ops, X=6 ops):
            if (qt == 0 && k <= 1)                   asm volatile("s_waitcnt vmcnt(6)"  ::: "memory");
            else if ((qt == 1 || qt == 2) && k <= 1) asm volatile("s_waitcnt vmcnt(10)" ::: "memory");
            else if (sl == 35)                       asm volatile("s_waitcnt vmcnt(0)"  ::: "memory");
            else                                     asm volatile("s_waitcnt vmcnt(4)"  ::: "memory");
            __builtin_amdgcn_sched_barrier(0);
            __builtin_amdgcn_s_barrier();

            const int dy = (k * 11) >> 5;
            const int dx = k - dy * 3;
            const int doff = dy * 18 + dx;
            const char* wbuf = smem + WOFF + ((sl & 1) ? WSL : 0);
            const unsigned mk = mbits >> (k * 2);

            int sx[2];
            #pragma unroll
            for (int n = 0; n < 2; ++n) sx[n] = sB[n] + doff;

            __builtin_amdgcn_s_setprio(1);
            #pragma unroll
            for (int ks = 0; ks < 4; ++ks) {
                const int ua = ks * 2 + khalf;
                bf16x8 av[4];
                #pragma unroll
                for (int mo = 0; mo < 4; ++mo)
                    av[mo] = *(const bf16x8*)(wbuf + abase[mo] + ((ua ^ aswz[mo]) << 4));
                bf16x8 bv[2];
                #pragma unroll
                for (int n = 0; n < 2; ++n) {
                    i32x4 braw = *(const i32x4*)(xbuf + sx[n] * 128 + ((ua ^ (sx[n] & 7)) << 4));
                    const int mm = -(int)((mk >> n) & 1u);
                    #pragma unroll
                    for (int w4 = 0; w4 < 4; ++w4) braw[w4] &= mm;   // binary mask, exact
                    bv[n] = __builtin_bit_cast(bf16x8, braw);
                }
                #pragma unroll
                for (int mo = 0; mo < 4; ++mo)
                    #pragma unroll
                    for (int n = 0; n < 2; ++n)
                        acc[mo][n] = __builtin_amdgcn_mfma_f32_32x32x16_bf16(av[mo], bv[n], acc[mo][n], 0, 0, 0);
            }
            __builtin_amdgcn_s_setprio(0);

            asm volatile("" ::: "memory");
            __builtin_amdgcn_s_barrier();
            if (sl + 2 < 36)
                stage_w(wb, smem, WOFF + ((sl & 1) ? WSL : 0), sl + 2, wid, l);
            if (k == 8 && qt < 2)
                stage_x(hi_in, zb, smem, (qt & 1) ? XSZ : 0, b, tr, tc, qt + 2, wid, l);
        }
    }

    // ---- epilogue: two 128-KB phases (rows 0-7 then 8-15); LDS transpose.
    // Non-final: coalesced hi/lo shadow RMW.  Final: xn -> LDS, then channel-major
    // readout writes fp32 NCHW directly (saves the separate transpose kernel).
    __syncthreads();
    #pragma unroll 1
    for (int ph = 0; ph < 2; ++ph) {
        if ((wave_p >> 1) == ph) {
            #pragma unroll
            for (int n = 0; n < 2; ++n) {
                const int row_local = (wave_p & 1) * 4 + n * 2 + rowin;  // 0..7
                const int pl = row_local * 16 + col;                      // 0..127
                #pragma unroll
                for (int rq = 0; rq < 4; ++rq) {
                    #pragma unroll
                    for (int mo = 0; mo < 4; ++mo) {
                        const int u = wave_o * 32 + mo * 8 + rq * 2 + khalf;  // ch unit
                        f32x4 v;
                        v[0] = acc[mo][n][rq * 4 + 0];
                        v[1] = acc[mo][n][rq * 4 + 1];
                        v[2] = acc[mo][n][rq * 4 + 2];
                        v[3] = acc[mo][n][rq * 4 + 3];
                        *(f32x4*)(smem + pl * 1024 + ((u ^ (pl & 7)) << 4)) = v;
                    }
                }
            }
        }
        __syncthreads();
        #pragma unroll 2
        for (int it = 0; it < 16; ++it) {
            const int pl = it * 8 + wid;                 // pl & 7 == wid
            const int h = tr * 16 + ph * 8 + (pl >> 4);
            const int w = tc * 16 + (pl & 15);
            const int laddr = pl * 1024 + ((l ^ wid) << 4);
            const f32x4 d4 = *(const f32x4*)(smem + laddr);
            const size_t base = (((size_t)((b * 128 + h) * 128 + w)) << 8) + l * 4;
            const u16x4 h4 = *(const u16x4*)(hi_in + base);
            const u16x4 l4 = *(const u16x4*)(lo_in + base);
            if (!final_step) {
                u16x4 ho, lo2;
                #pragma unroll
                for (int r = 0; r < 4; ++r) {
                    const float xv = bf2f(h4[r]) + bf2f(l4[r]);
                    const float d = d4[r];
                    const float xn = xv + d / (1.f + fabsf(d));
                    ho[r] = f2bf_rne(xn);
                    lo2[r] = f2bf_rne(xn - bf2f(ho[r]));
                }
                *(u16x4*)(hi_out + base) = ho;
                *(u16x4*)(lo_out + base) = lo2;
            } else {
                f32x4 xn;
                #pragma unroll
                for (int r = 0; r < 4; ++r) {
                    const float xv = bf2f(h4[r]) + bf2f(l4[r]);
                    const float d = d4[r];
                    xn[r] = xv + d / (1.f + fabsf(d));
                }
                *(f32x4*)(smem + laddr) = xn;            // overwrite delta with xn
            }
        }
        if (final_step) {
            __syncthreads();
            // channel-major readout: wave wid owns tile-row wid of this phase.
            // lane = col(16) x ch-sub(4); per i: 4 channels x 16 w, coalesced 64-B runs.
            const int colr = l & 15, chs = l >> 4;
            const int px = wid * 16 + colr;
            const int h = tr * 16 + ph * 8 + wid;
            const int w = tc * 16 + colr;
            #pragma unroll 4
            for (int g = 0; g < 64; ++g) {               // channel unit
                const float v = *(const float*)(smem + px * 1024
                                + ((g ^ (px & 7)) << 4) + chs * 4);
                const int ch = g * 4 + chs;
                out_f32[((size_t)(b * C_ + ch) * H_ + h) * W_ + w] = v;
            }
        }
        if (ph == 0) __syncthreads();
    }
}

// ================= fp32 fallback (only if ws too small) =================
#define OT 64
#define TR 4
#define TC 16
#define CKC 16
__global__ __launch_bounds__(256)
void nca_step_f32(const float* __restrict__ xin, const float* __restrict__ wg,
                  const float* __restrict__ mask, float* __restrict__ xout)
{
    __shared__ __align__(16) float w_s[CKC][9][OT];
    __shared__ __align__(16) float x_s[CKC][TR + 2][20];
    const int tid = threadIdx.x;
    int bt = blockIdx.x;
    const int col_tile = bt & 7;  bt >>= 3;
    const int row_tile = bt & 31; bt >>= 5;
    const int ot = bt & 3;        const int b = bt >> 2;
    const int gr0 = row_tile * TR, gc0 = col_tile * TC, o_base = ot * OT;
    const int og = tid >> 4, pg = tid & 15;
    const int prow = pg >> 2, pcol4 = (pg & 3) * 4;
    const int orow = gr0 + prow, ocol0 = gc0 + pcol4;
    float mask_r[9][4];
#pragma unroll
    for (int k = 0; k < 9; ++k)
#pragma unroll
        for (int j = 0; j < 4; ++j)
            mask_r[k][j] = mask[k * NPIX + orow * W_ + (ocol0 + j)];
    float acc[4][4];
#pragma unroll
    for (int a = 0; a < 4; ++a)
#pragma unroll
        for (int j = 0; j < 4; ++j) acc[a][j] = 0.f;
    for (int chunk = 0; chunk < C_ / CKC; ++chunk) {
        const int c0 = chunk * CKC;
#pragma unroll
        for (int i = 0; i < 36; ++i) {
            const int flat = i * 256 + tid;
            const int o_l = flat / 144;
            const int r = flat - o_l * 144;
            const int c_l = r / 9;
            const int kk = r - c_l * 9;
            w_s[c_l][kk][o_l] = wg[(o_base + o_l) * (C_ * 9) + (c0 + c_l) * 9 + kk];
        }
#pragma unroll
        for (int i = 0; i < 7; ++i) {
            const int flat = i * 256 + tid;
            if (flat < CKC * 108) {
                const int c_l = flat / 108;
                const int r = flat - c_l * 108;
                const int row = r / 18, colx = r - row * 18;
                const int grow = gr0 - 1 + row, gcol = gc0 - 1 + colx;
                float v = 0.f;
                if ((unsigned)grow < (unsigned)H_ && (unsigned)gcol < (unsigned)W_)
                    v = xin[((b * C_ + c0 + c_l) * H_ + grow) * W_ + gcol];
                x_s[c_l][row][colx] = v;
            }
        }
        __syncthreads();
#pragma unroll
        for (int dyy = 0; dyy < 3; ++dyy) {
            float acck[3][4][4];
#pragma unroll
            for (int dxx = 0; dxx < 3; ++dxx)
#pragma unroll
                for (int a = 0; a < 4; ++a)
#pragma unroll
                    for (int j = 0; j < 4; ++j) acck[dxx][a][j] = 0.f;
#pragma unroll 4
            for (int c = 0; c < CKC; ++c) {
                const float4 xv4 = *(const float4*)&x_s[c][prow + dyy][pcol4];
                const float2 xv2 = *(const float2*)&x_s[c][prow + dyy][pcol4 + 4];
                const float xv[6] = {xv4.x, xv4.y, xv4.z, xv4.w, xv2.x, xv2.y};
#pragma unroll
                for (int dxx = 0; dxx < 3; ++dxx) {
                    const float4 wv = *(const float4*)&w_s[c][dyy * 3 + dxx][og * 4];
                    const float wa[4] = {wv.x, wv.y, wv.z, wv.w};
#pragma unroll
                    for (int a = 0; a < 4; ++a)
#pragma unroll
                        for (int j = 0; j < 4; ++j)
                            acck[dxx][a][j] = fmaf(wa[a], xv[j + dxx], acck[dxx][a][j]);
                }
            }
#pragma unroll
            for (int dxx = 0; dxx < 3; ++dxx) {
                const int k = dyy * 3 + dxx;
#pragma unroll
                for (int a = 0; a < 4; ++a)
#pragma unroll
                    for (int j = 0; j < 4; ++j)
                        acc[a][j] = fmaf(mask_r[k][j], acck[dxx][a][j], acc[a][j]);
            }
        }
        __syncthreads();
    }
#pragma unroll
    for (int a = 0; a < 4; ++a) {
        const int o = o_base + og * 4 + a;
#pragma unroll
        for (int j = 0; j < 4; ++j) {
            const int idx = ((b * C_ + o) * H_ + orow) * W_ + (ocol0 + j);
            const float d = acc[a][j];
            xout[idx] = xin[idx] + d / (1.0f + fabsf(d));
        }
    }
}

extern "C" void kernel_launch(void* const* d_in, const int* in_sizes, int n_in,
                              void* d_out, int out_size, void* d_ws, size_t ws_size,
                              hipStream_t stream) {
    const float* retina = (const float*)d_in[0];
    const float* wg     = (const float*)d_in[1];
    const float* mask   = (const float*)d_in[2];
    float* out = (float*)d_out;

    const size_t need = 0x4200000;   // wb+zb (2M) + hiA/loA (2x32M)

    if (ws_size >= need) {
        unsigned short* wb  = (unsigned short*)d_ws;
        unsigned short* zb  = (unsigned short*)((char*)d_ws + 0x120000);
        unsigned short* hiA = (unsigned short*)((char*)d_ws + 0x200000);
        unsigned short* loA = (unsigned short*)((char*)d_ws + 0x2200000);
        unsigned short* hiB = (unsigned short*)d_out;              // first 32 MB of out
        unsigned short* loB = hiB + (size_t)B_ * NPIX * C_;        // second 32 MB

        hipFuncSetAttribute((const void*)nca_v13,
                            hipFuncAttributeMaxDynamicSharedMemorySize, LDS_TOTAL);

        prep_w<<<2305, 256, 0, stream>>>(wg, wb, zb);
        prep_split<<<4096, 256, 0, stream>>>(retina, hiA, loA);    // state starts in A (ws)

        // A->B->A->B->A, then final step A -> fp32 d_out (fused, no transpose kernel)
        nca_v13<<<256, 512, LDS_TOTAL, stream>>>(hiA, loA, wb, zb, mask, hiB, loB, out, 0);
        nca_v13<<<256, 512, LDS_TOTAL, stream>>>(hiB, loB, wb, zb, mask, hiA, loA, out, 0);
        nca_v13<<<256, 512, LDS_TOTAL, stream>>>(hiA, loA, wb, zb, mask, hiB, loB, out, 0);
        nca_v13<<<256, 512, LDS_TOTAL, stream>>>(hiB, loB, wb, zb, mask, hiA, loA, out, 0);
        nca_v13<<<256, 512, LDS_TOTAL, stream>>>(hiA, loA, wb, zb, mask, hiB, loB, out, 1);
    } else {
        float* ws = (float*)d_ws;
        const int nblocks = B_ * (C_ / OT) * (H_ / TR) * (W_ / TC);
        const float* src = retina;
        float* dsts[5] = {out, ws, out, ws, out};
        for (int s = 0; s < 5; ++s) {
            nca_step_f32<<<dim3(nblocks), dim3(256), 0, stream>>>(src, wg, mask, dsts[s]);
            src = dsts[s];
        }
    }
}